// Round 1
// baseline (1643.490 us; speedup 1.0000x reference)
//
#include <hip/hip_runtime.h>
#include <math.h>

// Problem constants (B=2, L=2048, D=512)
#define BB 2
#define LL 2048
#define DD 512
#define DIN 1024          // D_INNER
#define DXZ 2048          // 2*D_INNER
#define DSTATE 16
#define DTRANK 32
#define NDBL 64           // DT_RANK + 2*D_STATE
#define ML (BB*LL)        // 4096 rows

// ---------------------------------------------------------------------------
// Generic fp32 tiled GEMM: C[M,N] = A[M,K] * B[K,N]  (64x64 tile, BK=16,
// 256 threads, 4x4 per thread). MODE 0: plain; MODE 1: softplus(acc+bias[n]);
// MODE 2: acc + aux[m*ldc+n] (residual).
// All of our shapes are multiples of the tile sizes -> no edge guards.
// ---------------------------------------------------------------------------
template <int MODE>
__launch_bounds__(256)
__global__ void gemm_tiled(const float* __restrict__ A, int lda,
                           const float* __restrict__ B, int ldb,
                           float* __restrict__ C, int ldc,
                           int M, int N, int K,
                           const float* __restrict__ aux) {
  __shared__ float As[16][68];   // [k][m], row stride 68 (16B-aligned rows)
  __shared__ float Bs[16][68];   // [k][n]

  const int tid = threadIdx.x;
  const int tx = tid & 15, ty = tid >> 4;
  const int mBase = blockIdx.y * 64;
  const int nBase = blockIdx.x * 64;

  float acc[4][4] = {};

  for (int k0 = 0; k0 < K; k0 += 16) {
#pragma unroll
    for (int i = 0; i < 4; i++) {
      int idx = tid + i * 256;          // 0..1023 over 64m x 16k
      int m = idx >> 4, kk = idx & 15;
      As[kk][m] = A[(size_t)(mBase + m) * lda + k0 + kk];
    }
#pragma unroll
    for (int i = 0; i < 4; i++) {
      int idx = tid + i * 256;          // 0..1023 over 16k x 64n
      int kk = idx >> 6, n = idx & 63;
      Bs[kk][n] = B[(size_t)(k0 + kk) * ldb + nBase + n];
    }
    __syncthreads();
#pragma unroll
    for (int kk = 0; kk < 16; kk++) {
      const float4 a4 = *reinterpret_cast<const float4*>(&As[kk][ty * 4]);
      const float4 b4 = *reinterpret_cast<const float4*>(&Bs[kk][tx * 4]);
      const float a[4] = {a4.x, a4.y, a4.z, a4.w};
      const float b[4] = {b4.x, b4.y, b4.z, b4.w};
#pragma unroll
      for (int i = 0; i < 4; i++)
#pragma unroll
        for (int j = 0; j < 4; j++) acc[i][j] = fmaf(a[i], b[j], acc[i][j]);
    }
    __syncthreads();
  }

#pragma unroll
  for (int i = 0; i < 4; i++) {
    const int m = mBase + ty * 4 + i;
    const int n0 = nBase + tx * 4;
    float v[4];
#pragma unroll
    for (int j = 0; j < 4; j++) {
      float x = acc[i][j];
      if (MODE == 1) {
        x += aux[n0 + j];                       // bias over N
        x = (x > 20.f) ? x : log1pf(expf(x));   // softplus
      } else if (MODE == 2) {
        x += aux[(size_t)m * ldc + n0 + j];     // residual (same layout as C)
      }
      v[j] = x;
    }
    *reinterpret_cast<float4*>(&C[(size_t)m * ldc + n0]) =
        make_float4(v[0], v[1], v[2], v[3]);
  }
}

// ---------------------------------------------------------------------------
// Depthwise causal conv (k=4) + bias + SiLU.
// Reads u-part of xz (cols 0..1023 of the 2048-wide buffer), writes u[ML,1024].
// out[l] = sum_{k=0..3} in[l-3+k] * w[d,k]
// ---------------------------------------------------------------------------
__global__ void conv_silu_kernel(const float* __restrict__ xz,
                                 const float* __restrict__ conv_w,
                                 const float* __restrict__ conv_b,
                                 float* __restrict__ u) {
  int idx = blockIdx.x * 256 + threadIdx.x;      // over ML*1024
  if (idx >= ML * DIN) return;
  int d = idx & (DIN - 1);
  int bl = idx >> 10;                            // b*L + l
  int l = bl & (LL - 1);
  const float w0 = conv_w[d * 4 + 0], w1 = conv_w[d * 4 + 1];
  const float w2 = conv_w[d * 4 + 2], w3 = conv_w[d * 4 + 3];
  const float* base = xz + (size_t)bl * DXZ + d;
  float acc = conv_b[d] + w3 * base[0];
  if (l >= 1) acc = fmaf(w2, base[-1 * DXZ], acc);
  if (l >= 2) acc = fmaf(w1, base[-2 * DXZ], acc);
  if (l >= 3) acc = fmaf(w0, base[-3 * DXZ], acc);
  u[idx] = acc / (1.f + expf(-acc));             // silu
}

// ---------------------------------------------------------------------------
// Selective scan. One channel (b,d) per 16 lanes; lane s holds state s.
// h = h*exp(dt*A[s]) + dt*u*B[s];  y = sum_s h*C[s]
// Epilogue fused: yc = (y + u*D_param) * silu(z); written into the (dead)
// u-half of the xz buffer so the output GEMM can read it with lda=2048.
// ---------------------------------------------------------------------------
__launch_bounds__(256)
__global__ void scan_kernel(const float* __restrict__ dt,
                            const float* __restrict__ u,
                            const float* __restrict__ xdbl,
                            float* xz,   // z read (cols 1024..2047), y write (cols 0..1023)
                            const float* __restrict__ A_log,
                            const float* __restrict__ D_param) {
  const int tid = threadIdx.x;
  const int ch = tid >> 4, s = tid & 15;
  const int c = blockIdx.x * 16 + ch;     // channel 0..2047
  const int b = c >> 10;
  const int d = c & (DIN - 1);

  const float Al2 = -expf(A_log[d * DSTATE + s]) * 1.44269504f;  // A[s]*log2(e)
  const float Dp = D_param[d];
  const size_t bl = (size_t)b * LL;

  float h = 0.f;
  // 1-step prefetch to hide global latency off the h-chain
  float dt_n = dt[bl * DIN + d];
  float u_n = u[bl * DIN + d];
  float B_n = xdbl[bl * NDBL + DTRANK + s];
  float C_n = xdbl[bl * NDBL + DTRANK + DSTATE + s];

  for (int l = 0; l < LL; l++) {
    const float dt_v = dt_n, u_v = u_n, Bv = B_n, Cv = C_n;
    if (l + 1 < LL) {
      const size_t nb = bl + l + 1;
      dt_n = dt[nb * DIN + d];
      u_n = u[nb * DIN + d];
      B_n = xdbl[nb * NDBL + DTRANK + s];
      C_n = xdbl[nb * NDBL + DTRANK + DSTATE + s];
    }
    const float dA = exp2f(dt_v * Al2);
    h = fmaf(h, dA, dt_v * u_v * Bv);
    float p = h * Cv;
    p += __shfl_xor(p, 1);
    p += __shfl_xor(p, 2);
    p += __shfl_xor(p, 4);
    p += __shfl_xor(p, 8);
    if (s == 0) {
      const size_t cb = bl + l;
      const float zv = xz[cb * DXZ + DIN + d];
      const float sig = 1.f / (1.f + expf(-zv));
      xz[cb * DXZ + d] = (p + u_v * Dp) * (zv * sig);
    }
  }
}

// ---------------------------------------------------------------------------
extern "C" void kernel_launch(void* const* d_in, const int* in_sizes, int n_in,
                              void* d_out, int out_size, void* d_ws, size_t ws_size,
                              hipStream_t stream) {
  const float* x      = (const float*)d_in[0];  // (B,L,D)
  const float* W_in   = (const float*)d_in[1];  // (D, 2048)
  const float* conv_w = (const float*)d_in[2];  // (1024,4)
  const float* conv_b = (const float*)d_in[3];  // (1024,)
  const float* W_x    = (const float*)d_in[4];  // (1024,64)
  const float* W_dt   = (const float*)d_in[5];  // (32,1024)
  const float* b_dt   = (const float*)d_in[6];  // (1024,)
  const float* A_log  = (const float*)d_in[7];  // (1024,16)
  const float* D_par  = (const float*)d_in[8];  // (1024,)
  const float* W_out  = (const float*)d_in[9];  // (1024,512)
  float* out = (float*)d_out;

  char* ws = (char*)d_ws;
  float* xz    = (float*)(ws);                                  // 4096x2048 (32MB)
  float* u_buf = (float*)(ws + (size_t)ML * DXZ * 4);           // 4096x1024 (16MB)
  float* x_dbl = (float*)(ws + (size_t)ML * (DXZ + DIN) * 4);   // 4096x64   (1MB)
  float* dt_b  = (float*)(ws + (size_t)ML * (DXZ + DIN + NDBL) * 4); // 4096x1024 (16MB)

  // 1) xz = x @ W_in            (4096x512)@(512x2048)
  gemm_tiled<0><<<dim3(DXZ / 64, ML / 64), 256, 0, stream>>>(
      x, DD, W_in, DXZ, xz, DXZ, ML, DXZ, DD, nullptr);

  // 2) u = silu(causal_conv4(xz[:, :1024]) + conv_b)
  conv_silu_kernel<<<(ML * DIN) / 256, 256, 0, stream>>>(xz, conv_w, conv_b, u_buf);

  // 3) x_dbl = u @ W_x          (4096x1024)@(1024x64)
  gemm_tiled<0><<<dim3(NDBL / 64, ML / 64), 256, 0, stream>>>(
      u_buf, DIN, W_x, NDBL, x_dbl, NDBL, ML, NDBL, DIN, nullptr);

  // 4) dt = softplus(x_dbl[:, :32] @ W_dt + b_dt)   (4096x32)@(32x1024)
  gemm_tiled<1><<<dim3(DIN / 64, ML / 64), 256, 0, stream>>>(
      x_dbl, NDBL, W_dt, DIN, dt_b, DIN, ML, DIN, DTRANK, b_dt);

  // 5) selective scan + gated epilogue -> xz[:, :1024]
  scan_kernel<<<(BB * DIN) / 16, 256, 0, stream>>>(
      dt_b, u_buf, x_dbl, xz, A_log, D_par);

  // 6) out = x + y_comb @ W_out  (4096x1024)@(1024x512)
  gemm_tiled<2><<<dim3(DD / 64, ML / 64), 256, 0, stream>>>(
      xz, DXZ, W_out, DD, out, DD, ML, DD, DIN, x);
}

// Round 2
// 593.788 us; speedup vs baseline: 2.7678x; 2.7678x over previous
//
#include <hip/hip_runtime.h>
#include <math.h>

// Problem constants (B=2, L=2048, D=512)
#define BB 2
#define LL 2048
#define DD 512
#define DIN 1024          // D_INNER
#define DXZ 2048          // 2*D_INNER
#define DSTATE 16
#define DTRANK 32
#define NDBL 64           // DT_RANK + 2*D_STATE
#define ML (BB*LL)        // 4096 rows
#define LC 128            // scan chunk length
#define NCHUNK (LL/LC)    // 16 chunks per sequence

// ---------------------------------------------------------------------------
// Generic fp32 tiled GEMM: C[M,N] = A[M,K] * B[K,N]  (64x64 tile, BK=16,
// 256 threads, 4x4 per thread). MODE 0: plain; MODE 1: softplus(acc+bias[n]);
// MODE 2: acc + aux[m*ldc+n] (residual).
// ---------------------------------------------------------------------------
template <int MODE>
__launch_bounds__(256)
__global__ void gemm_tiled(const float* __restrict__ A, int lda,
                           const float* __restrict__ B, int ldb,
                           float* __restrict__ C, int ldc,
                           int M, int N, int K,
                           const float* __restrict__ aux) {
  __shared__ float As[16][68];   // [k][m]
  __shared__ float Bs[16][68];   // [k][n]

  const int tid = threadIdx.x;
  const int tx = tid & 15, ty = tid >> 4;
  const int mBase = blockIdx.y * 64;
  const int nBase = blockIdx.x * 64;

  float acc[4][4] = {};

  for (int k0 = 0; k0 < K; k0 += 16) {
#pragma unroll
    for (int i = 0; i < 4; i++) {
      int idx = tid + i * 256;          // 64m x 16k
      int m = idx >> 4, kk = idx & 15;
      As[kk][m] = A[(size_t)(mBase + m) * lda + k0 + kk];
    }
#pragma unroll
    for (int i = 0; i < 4; i++) {
      int idx = tid + i * 256;          // 16k x 64n
      int kk = idx >> 6, n = idx & 63;
      Bs[kk][n] = B[(size_t)(k0 + kk) * ldb + nBase + n];
    }
    __syncthreads();
#pragma unroll
    for (int kk = 0; kk < 16; kk++) {
      const float4 a4 = *reinterpret_cast<const float4*>(&As[kk][ty * 4]);
      const float4 b4 = *reinterpret_cast<const float4*>(&Bs[kk][tx * 4]);
      const float a[4] = {a4.x, a4.y, a4.z, a4.w};
      const float b[4] = {b4.x, b4.y, b4.z, b4.w};
#pragma unroll
      for (int i = 0; i < 4; i++)
#pragma unroll
        for (int j = 0; j < 4; j++) acc[i][j] = fmaf(a[i], b[j], acc[i][j]);
    }
    __syncthreads();
  }

#pragma unroll
  for (int i = 0; i < 4; i++) {
    const int m = mBase + ty * 4 + i;
    const int n0 = nBase + tx * 4;
    float v[4];
#pragma unroll
    for (int j = 0; j < 4; j++) {
      float x = acc[i][j];
      if (MODE == 1) {
        x += aux[n0 + j];
        x = (x > 20.f) ? x : log1pf(expf(x));
      } else if (MODE == 2) {
        x += aux[(size_t)m * ldc + n0 + j];
      }
      v[j] = x;
    }
    *reinterpret_cast<float4*>(&C[(size_t)m * ldc + n0]) =
        make_float4(v[0], v[1], v[2], v[3]);
  }
}

// ---------------------------------------------------------------------------
// Depthwise causal conv (k=4) + bias + SiLU.
// ---------------------------------------------------------------------------
__global__ void conv_silu_kernel(const float* __restrict__ xz,
                                 const float* __restrict__ conv_w,
                                 const float* __restrict__ conv_b,
                                 float* __restrict__ u) {
  int idx = blockIdx.x * 256 + threadIdx.x;      // over ML*1024
  if (idx >= ML * DIN) return;
  int d = idx & (DIN - 1);
  int bl = idx >> 10;                            // b*L + l
  int l = bl & (LL - 1);
  const float w0 = conv_w[d * 4 + 0], w1 = conv_w[d * 4 + 1];
  const float w2 = conv_w[d * 4 + 2], w3 = conv_w[d * 4 + 3];
  const float* base = xz + (size_t)bl * DXZ + d;
  float acc = conv_b[d] + w3 * base[0];
  if (l >= 1) acc = fmaf(w2, base[-1 * DXZ], acc);
  if (l >= 2) acc = fmaf(w1, base[-2 * DXZ], acc);
  if (l >= 3) acc = fmaf(w0, base[-3 * DXZ], acc);
  u[idx] = acc / (1.f + expf(-acc));             // silu
}

// ---------------------------------------------------------------------------
// Chunked selective scan.
// Phase 1: per (channel, chunk), 16 lanes (one state each): local scan with
//          h0=0 -> write end-state Hloc and decay product P.
// ---------------------------------------------------------------------------
__launch_bounds__(256)
__global__ void scan_phase1(const float* __restrict__ dt,
                            const float* __restrict__ u,
                            const float* __restrict__ xdbl,
                            const float* __restrict__ A_log,
                            float* __restrict__ Pout,
                            float* __restrict__ Hout) {
  const int tid = threadIdx.x;
  const int g = blockIdx.x * 16 + (tid >> 4);   // group over NC*NCHUNK
  const int s = tid & 15;
  const int chunk = g & (NCHUNK - 1);
  const int c = g >> 4;                         // channel (NCHUNK==16)
  const int b = c >> 10, d = c & (DIN - 1);

  const float Al2 = -expf(A_log[d * DSTATE + s]) * 1.44269504f;
  const size_t l0 = (size_t)b * LL + (size_t)chunk * LC;

  float h = 0.f, P = 1.f;
#pragma unroll 4
  for (int l = 0; l < LC; l++) {
    const size_t idx = l0 + l;
    const float dt_v = dt[idx * DIN + d];
    const float u_v  = u[idx * DIN + d];
    const float Bv   = xdbl[idx * NDBL + DTRANK + s];
    const float dA = exp2f(dt_v * Al2);
    P *= dA;
    h = fmaf(h, dA, dt_v * u_v * Bv);
  }
  Pout[(size_t)g * DSTATE + s] = P;
  Hout[(size_t)g * DSTATE + s] = h;
}

// Phase 2: per (channel, state), serial combine over NCHUNK chunks:
//          Hin[chunk] = running h before the chunk;  h = P*h + Hloc.
__launch_bounds__(256)
__global__ void scan_phase2(const float* __restrict__ P,
                            const float* __restrict__ Hloc,
                            float* __restrict__ Hin) {
  const int t = blockIdx.x * 256 + threadIdx.x;   // over NC*DSTATE
  const int s = t & 15;
  const int c = t >> 4;
  float h = 0.f;
#pragma unroll
  for (int ch = 0; ch < NCHUNK; ch++) {
    const size_t g = (size_t)c * NCHUNK + ch;
    Hin[g * DSTATE + s] = h;
    h = fmaf(h, P[g * DSTATE + s], Hloc[g * DSTATE + s]);
  }
}

// Phase 3: re-run recurrence from Hin, produce y, fused gated epilogue:
//          yc = (y + u*D_param) * silu(z)  -> written into xz[:, :1024].
__launch_bounds__(256)
__global__ void scan_phase3(const float* __restrict__ dt,
                            const float* __restrict__ u,
                            const float* __restrict__ xdbl,
                            float* xz,
                            const float* __restrict__ A_log,
                            const float* __restrict__ D_param,
                            const float* __restrict__ Hin) {
  const int tid = threadIdx.x;
  const int g = blockIdx.x * 16 + (tid >> 4);
  const int s = tid & 15;
  const int chunk = g & (NCHUNK - 1);
  const int c = g >> 4;
  const int b = c >> 10, d = c & (DIN - 1);

  const float Al2 = -expf(A_log[d * DSTATE + s]) * 1.44269504f;
  const float Dp = D_param[d];
  const size_t l0 = (size_t)b * LL + (size_t)chunk * LC;

  float h = Hin[(size_t)g * DSTATE + s];
#pragma unroll 2
  for (int l = 0; l < LC; l++) {
    const size_t idx = l0 + l;
    const float dt_v = dt[idx * DIN + d];
    const float u_v  = u[idx * DIN + d];
    const float Bv   = xdbl[idx * NDBL + DTRANK + s];
    const float Cv   = xdbl[idx * NDBL + DTRANK + DSTATE + s];
    const float dA = exp2f(dt_v * Al2);
    h = fmaf(h, dA, dt_v * u_v * Bv);
    float p = h * Cv;
    p += __shfl_xor(p, 1);
    p += __shfl_xor(p, 2);
    p += __shfl_xor(p, 4);
    p += __shfl_xor(p, 8);
    if (s == 0) {
      const float zv = xz[idx * DXZ + DIN + d];
      const float sig = 1.f / (1.f + expf(-zv));
      xz[idx * DXZ + d] = (p + u_v * Dp) * (zv * sig);
    }
  }
}

// ---------------------------------------------------------------------------
extern "C" void kernel_launch(void* const* d_in, const int* in_sizes, int n_in,
                              void* d_out, int out_size, void* d_ws, size_t ws_size,
                              hipStream_t stream) {
  const float* x      = (const float*)d_in[0];  // (B,L,D)
  const float* W_in   = (const float*)d_in[1];  // (D, 2048)
  const float* conv_w = (const float*)d_in[2];  // (1024,4)
  const float* conv_b = (const float*)d_in[3];  // (1024,)
  const float* W_x    = (const float*)d_in[4];  // (1024,64)
  const float* W_dt   = (const float*)d_in[5];  // (32,1024)
  const float* b_dt   = (const float*)d_in[6];  // (1024,)
  const float* A_log  = (const float*)d_in[7];  // (1024,16)
  const float* D_par  = (const float*)d_in[8];  // (1024,)
  const float* W_out  = (const float*)d_in[9];  // (1024,512)
  float* out = (float*)d_out;

  char* ws = (char*)d_ws;
  float* xz    = (float*)(ws);                                  // 4096x2048 (32MB)
  float* u_buf = (float*)(ws + (size_t)ML * DXZ * 4);           // 4096x1024 (16MB)
  float* x_dbl = (float*)(ws + (size_t)ML * (DXZ + DIN) * 4);   // 4096x64   (1MB)
  float* dt_b  = (float*)(ws + (size_t)ML * (DXZ + DIN + NDBL) * 4); // 4096x1024 (16MB)
  size_t off = (size_t)ML * (DXZ + DIN + NDBL + DIN) * 4;
  const size_t NG = (size_t)BB * DIN * NCHUNK;                  // 32768 groups
  float* P_buf = (float*)(ws + off);                            // NG x 16 (2MB)
  float* H_loc = (float*)(ws + off + NG * DSTATE * 4);          // NG x 16 (2MB)
  float* H_in  = (float*)(ws + off + 2 * NG * DSTATE * 4);      // NG x 16 (2MB)

  // 1) xz = x @ W_in            (4096x512)@(512x2048)
  gemm_tiled<0><<<dim3(DXZ / 64, ML / 64), 256, 0, stream>>>(
      x, DD, W_in, DXZ, xz, DXZ, ML, DXZ, DD, nullptr);

  // 2) u = silu(causal_conv4(xz[:, :1024]) + conv_b)
  conv_silu_kernel<<<(ML * DIN) / 256, 256, 0, stream>>>(xz, conv_w, conv_b, u_buf);

  // 3) x_dbl = u @ W_x          (4096x1024)@(1024x64)
  gemm_tiled<0><<<dim3(NDBL / 64, ML / 64), 256, 0, stream>>>(
      u_buf, DIN, W_x, NDBL, x_dbl, NDBL, ML, NDBL, DIN, nullptr);

  // 4) dt = softplus(x_dbl[:, :32] @ W_dt + b_dt)   (4096x32)@(32x1024)
  gemm_tiled<1><<<dim3(DIN / 64, ML / 64), 256, 0, stream>>>(
      x_dbl, NDBL, W_dt, DIN, dt_b, DIN, ML, DIN, DTRANK, b_dt);

  // 5) chunked selective scan + gated epilogue -> xz[:, :1024]
  scan_phase1<<<(int)(NG / 16), 256, 0, stream>>>(dt_b, u_buf, x_dbl, A_log, P_buf, H_loc);
  scan_phase2<<<(int)(BB * DIN * DSTATE / 256), 256, 0, stream>>>(P_buf, H_loc, H_in);
  scan_phase3<<<(int)(NG / 16), 256, 0, stream>>>(dt_b, u_buf, x_dbl, xz, A_log, D_par, H_in);

  // 6) out = x + y_comb @ W_out  (4096x1024)@(1024x512)
  gemm_tiled<2><<<dim3(DD / 64, ML / 64), 256, 0, stream>>>(
      xz, DXZ, W_out, DD, out, DD, ML, DD, DIN, x);
}

// Round 3
// 458.477 us; speedup vs baseline: 3.5847x; 1.2951x over previous
//
#include <hip/hip_runtime.h>
#include <math.h>

// Problem constants (B=2, L=2048, D=512)
#define BB 2
#define LL 2048
#define DD 512
#define DIN 1024          // D_INNER
#define DXZ 2048          // 2*D_INNER
#define DSTATE 16
#define DTRANK 32
#define NDBL 64           // DT_RANK + 2*D_STATE
#define ML (BB*LL)        // 4096 rows
#define LC 128            // scan chunk length
#define NCHUNK (LL/LC)    // 16 chunks per sequence
#define LCP 132           // padded LDS chunk stride (128+4: bank-conflict-free, float4-aligned)

// ---------------------------------------------------------------------------
// fp32 tiled GEMM: C = A*B, 64x64 tile, BK=16, 256 thr, 4x4/thread.
// AT: 0 -> A[m*lda+k], 1 -> A[k*lda+m] (transposed input layout)
// CT: 0 -> C[m*ldc+n], 1 -> C[n*ldc+m] (transposed output layout)
// MODE 0: plain; 1: softplus(acc+bias[n]); 2: acc+aux[m*ldc+n] (residual).
// ---------------------------------------------------------------------------
template <int MODE, int AT, int CT>
__launch_bounds__(256)
__global__ void gemm_tiled(const float* __restrict__ A, int lda,
                           const float* __restrict__ B, int ldb,
                           float* __restrict__ C, int ldc,
                           int M, int N, int K,
                           const float* __restrict__ aux) {
  __shared__ float As[16][68];   // [k][m]
  __shared__ float Bs[16][68];   // [k][n]

  const int tid = threadIdx.x;
  const int tx = tid & 15, ty = tid >> 4;
  const int mBase = blockIdx.y * 64;
  const int nBase = blockIdx.x * 64;

  float acc[4][4] = {};

  for (int k0 = 0; k0 < K; k0 += 16) {
#pragma unroll
    for (int i = 0; i < 4; i++) {
      int idx = tid + i * 256;
      if (AT == 0) {                      // 64m x 16k
        int m = idx >> 4, kk = idx & 15;
        As[kk][m] = A[(size_t)(mBase + m) * lda + k0 + kk];
      } else {                            // 16k x 64m (contiguous in m)
        int kk = idx >> 6, m = idx & 63;
        As[kk][m] = A[(size_t)(k0 + kk) * lda + mBase + m];
      }
    }
#pragma unroll
    for (int i = 0; i < 4; i++) {
      int idx = tid + i * 256;            // 16k x 64n
      int kk = idx >> 6, n = idx & 63;
      Bs[kk][n] = B[(size_t)(k0 + kk) * ldb + nBase + n];
    }
    __syncthreads();
#pragma unroll
    for (int kk = 0; kk < 16; kk++) {
      const float4 a4 = *reinterpret_cast<const float4*>(&As[kk][ty * 4]);
      const float4 b4 = *reinterpret_cast<const float4*>(&Bs[kk][tx * 4]);
      const float a[4] = {a4.x, a4.y, a4.z, a4.w};
      const float b[4] = {b4.x, b4.y, b4.z, b4.w};
#pragma unroll
      for (int i = 0; i < 4; i++)
#pragma unroll
        for (int j = 0; j < 4; j++) acc[i][j] = fmaf(a[i], b[j], acc[i][j]);
    }
    __syncthreads();
  }

  if (CT == 0) {
#pragma unroll
    for (int i = 0; i < 4; i++) {
      const int m = mBase + ty * 4 + i;
      const int n0 = nBase + tx * 4;
      float v[4];
#pragma unroll
      for (int j = 0; j < 4; j++) {
        float x = acc[i][j];
        if (MODE == 1) {
          x += aux[n0 + j];
          x = (x > 20.f) ? x : log1pf(expf(x));
        } else if (MODE == 2) {
          x += aux[(size_t)m * ldc + n0 + j];
        }
        v[j] = x;
      }
      *reinterpret_cast<float4*>(&C[(size_t)m * ldc + n0]) =
          make_float4(v[0], v[1], v[2], v[3]);
    }
  } else {
    const int m0 = mBase + ty * 4;
#pragma unroll
    for (int j = 0; j < 4; j++) {
      const int n = nBase + tx * 4 + j;
      float v[4];
#pragma unroll
      for (int i = 0; i < 4; i++) {
        float x = acc[i][j];
        if (MODE == 1) {
          x += aux[n];
          x = (x > 20.f) ? x : log1pf(expf(x));
        }
        v[i] = x;
      }
      *reinterpret_cast<float4*>(&C[(size_t)n * ldc + m0]) =
          make_float4(v[0], v[1], v[2], v[3]);
    }
  }
}

// ---------------------------------------------------------------------------
// Depthwise causal conv (k=4) + bias + SiLU, transposed layout.
// Reads xzT rows 0..1023 (pre-act u, contiguous in l), writes uT[DIN][ML].
// Each thread: 4 consecutive l of one channel d.
// ---------------------------------------------------------------------------
__launch_bounds__(256)
__global__ void conv_silu_T(const float* __restrict__ xzT,
                            const float* __restrict__ conv_w,
                            const float* __restrict__ conv_b,
                            float* __restrict__ uT) {
  const int idx = blockIdx.x * 256 + threadIdx.x;   // over DIN * ML/4
  const int d = idx >> 10;                          // ML/4 = 1024 slots/row
  const int ml0 = (idx & 1023) * 4;
  const int l0 = ml0 & (LL - 1);
  const float* row = xzT + (size_t)d * ML + ml0;
  const float4 Bv = *reinterpret_cast<const float4*>(row);
  float4 Av = make_float4(0.f, 0.f, 0.f, 0.f);
  if (l0 != 0) Av = *reinterpret_cast<const float4*>(row - 4);
  const float w0 = conv_w[d * 4 + 0], w1 = conv_w[d * 4 + 1];
  const float w2 = conv_w[d * 4 + 2], w3 = conv_w[d * 4 + 3];
  const float bias = conv_b[d];
  float o[4];
  o[0] = bias + w0 * Av.y + w1 * Av.z + w2 * Av.w + w3 * Bv.x;
  o[1] = bias + w0 * Av.z + w1 * Av.w + w2 * Bv.x + w3 * Bv.y;
  o[2] = bias + w0 * Av.w + w1 * Bv.x + w2 * Bv.y + w3 * Bv.z;
  o[3] = bias + w0 * Bv.x + w1 * Bv.y + w2 * Bv.z + w3 * Bv.w;
#pragma unroll
  for (int i = 0; i < 4; i++) o[i] = o[i] / (1.f + expf(-o[i]));  // silu
  *reinterpret_cast<float4*>(uT + (size_t)d * ML + ml0) =
      make_float4(o[0], o[1], o[2], o[3]);
}

// ---------------------------------------------------------------------------
// Fused chunked selective scan: one block = one (b,d) channel.
// LDS-staged dt/u/z rows (contiguous, chunk-padded). Phase1 local scans,
// phase2 chunk combine, phase3 re-scan + gated epilogue, y written back
// into the dead u-rows of xzT (transposed) for the output GEMM.
// ---------------------------------------------------------------------------
__launch_bounds__(256)
__global__ void scan_fused(const float* __restrict__ dtT,
                           const float* __restrict__ uT,
                           float* __restrict__ xzT,
                           const float* __restrict__ xdbl,
                           const float* __restrict__ A_log,
                           const float* __restrict__ D_param) {
  __shared__ float dt_s[NCHUNK * LCP];
  __shared__ float u_s[NCHUNK * LCP];
  __shared__ float zy_s[NCHUNK * LCP];
  __shared__ float Pc[NCHUNK][DSTATE];
  __shared__ float Hc[NCHUNK][DSTATE];
  __shared__ float Hin[NCHUNK][DSTATE];

  const int tid = threadIdx.x;
  const int c = blockIdx.x;
  const int b = c >> 10, d = c & (DIN - 1);
  const size_t rowoff = (size_t)d * ML + (size_t)b * LL;
  const float* dtrow = dtT + rowoff;
  const float* urow = uT + rowoff;
  const float* zrow = xzT + (size_t)(DIN + d) * ML + (size_t)b * LL;
  float* yrow = xzT + rowoff;

  // Stage 3 x 8KB rows, coalesced float4.
  for (int i = tid; i < 512; i += 256) {
    const int ch = i >> 5, off = (i & 31) * 4;
    const int la = ch * LCP + off;
    *reinterpret_cast<float4*>(&dt_s[la]) = *reinterpret_cast<const float4*>(&dtrow[i * 4]);
    *reinterpret_cast<float4*>(&u_s[la])  = *reinterpret_cast<const float4*>(&urow[i * 4]);
    *reinterpret_cast<float4*>(&zy_s[la]) = *reinterpret_cast<const float4*>(&zrow[i * 4]);
  }

  const int g = tid >> 4, s = tid & 15;
  const float Al2 = -expf(A_log[d * DSTATE + s]) * 1.44269504f;
  const float* dp = dt_s + g * LCP;
  const float* up = u_s + g * LCP;
  const float* BCp = xdbl + ((size_t)b * LL + (size_t)g * LC) * NDBL + DTRANK + s;
  __syncthreads();

  // Phase 1: local scan (h0=0), record end-state and decay product.
  {
    float h = 0.f, P = 1.f;
#pragma unroll 4
    for (int l = 0; l < LC; l++) {
      const float dtv = dp[l], uv = up[l];
      const float Bv = BCp[l * NDBL];
      const float dA = exp2f(dtv * Al2);
      P *= dA;
      h = fmaf(h, dA, dtv * uv * Bv);
    }
    Pc[g][s] = P;
    Hc[g][s] = h;
  }
  __syncthreads();

  // Phase 2: serial combine over chunks (16 threads).
  if (tid < DSTATE) {
    float h = 0.f;
#pragma unroll
    for (int ch = 0; ch < NCHUNK; ch++) {
      Hin[ch][tid] = h;
      h = fmaf(h, Pc[ch][tid], Hc[ch][tid]);
    }
  }
  __syncthreads();

  // Phase 3: re-scan from Hin, y + gated epilogue into zy_s in place.
  {
    const float Dp = D_param[d];
    float* zp = zy_s + g * LCP;
    float h = Hin[g][s];
#pragma unroll 2
    for (int l = 0; l < LC; l++) {
      const float dtv = dp[l], uv = up[l];
      const float Bv = BCp[l * NDBL];
      const float Cv = BCp[l * NDBL + DSTATE];
      const float dA = exp2f(dtv * Al2);
      h = fmaf(h, dA, dtv * uv * Bv);
      float p = h * Cv;
      p += __shfl_xor(p, 1);
      p += __shfl_xor(p, 2);
      p += __shfl_xor(p, 4);
      p += __shfl_xor(p, 8);
      if (s == 0) {
        const float zv = zp[l];
        const float sg = 1.f / (1.f + expf(-zv));
        zp[l] = (p + uv * Dp) * (zv * sg);
      }
    }
  }
  __syncthreads();

  // Store y row, coalesced float4.
  for (int i = tid; i < 512; i += 256) {
    const int ch = i >> 5, off = (i & 31) * 4;
    *reinterpret_cast<float4*>(&yrow[i * 4]) =
        *reinterpret_cast<const float4*>(&zy_s[ch * LCP + off]);
  }
}

// ---------------------------------------------------------------------------
extern "C" void kernel_launch(void* const* d_in, const int* in_sizes, int n_in,
                              void* d_out, int out_size, void* d_ws, size_t ws_size,
                              hipStream_t stream) {
  const float* x      = (const float*)d_in[0];  // (B,L,D)
  const float* W_in   = (const float*)d_in[1];  // (D, 2048)
  const float* conv_w = (const float*)d_in[2];  // (1024,4)
  const float* conv_b = (const float*)d_in[3];  // (1024,)
  const float* W_x    = (const float*)d_in[4];  // (1024,64)
  const float* W_dt   = (const float*)d_in[5];  // (32,1024)
  const float* b_dt   = (const float*)d_in[6];  // (1024,)
  const float* A_log  = (const float*)d_in[7];  // (1024,16)
  const float* D_par  = (const float*)d_in[8];  // (1024,)
  const float* W_out  = (const float*)d_in[9];  // (1024,512)
  float* out = (float*)d_out;

  char* ws = (char*)d_ws;
  float* xzT   = (float*)(ws);                                  // [2048][4096] 32MB
  float* uT    = (float*)(ws + (size_t)ML * DXZ * 4);           // [1024][4096] 16MB
  float* x_dbl = (float*)(ws + (size_t)ML * (DXZ + DIN) * 4);   // [4096][64]   1MB
  float* dtT   = (float*)(ws + (size_t)ML * (DXZ + DIN + NDBL) * 4); // [1024][4096] 16MB

  // 1) xzT = (x @ W_in)^T       (4096x512)@(512x2048) -> [2048][4096]
  gemm_tiled<0, 0, 1><<<dim3(DXZ / 64, ML / 64), 256, 0, stream>>>(
      x, DD, W_in, DXZ, xzT, ML, ML, DXZ, DD, nullptr);

  // 2) uT = silu(causal_conv4(xzT rows 0..1023) + conv_b)
  conv_silu_T<<<(DIN * (ML / 4)) / 256, 256, 0, stream>>>(xzT, conv_w, conv_b, uT);

  // 3) x_dbl = u @ W_x          A^T-layout input (uT), row-major output
  gemm_tiled<0, 1, 0><<<dim3(NDBL / 64, ML / 64), 256, 0, stream>>>(
      uT, ML, W_x, NDBL, x_dbl, NDBL, ML, NDBL, DIN, nullptr);

  // 4) dtT = softplus(x_dbl[:, :32] @ W_dt + b_dt)^T -> [1024][4096]
  gemm_tiled<1, 0, 1><<<dim3(DIN / 64, ML / 64), 256, 0, stream>>>(
      x_dbl, NDBL, W_dt, DIN, dtT, ML, ML, DIN, DTRANK, b_dt);

  // 5) fused chunked scan + gated epilogue -> xzT rows 0..1023 (= yT)
  scan_fused<<<BB * DIN, 256, 0, stream>>>(dtT, uT, xzT, x_dbl, A_log, D_par);

  // 6) out = x + y @ W_out      A^T-layout input (yT in xzT), row-major out
  gemm_tiled<2, 1, 0><<<dim3(DD / 64, ML / 64), 256, 0, stream>>>(
      xzT, ML, W_out, DD, out, DD, ML, DD, DIN, x);
}

// Round 4
// 310.000 us; speedup vs baseline: 5.3016x; 1.4790x over previous
//
#include <hip/hip_runtime.h>
#include <math.h>

// Problem constants (B=2, L=2048, D=512)
#define BB 2
#define LL 2048
#define DD 512
#define DIN 1024          // D_INNER
#define DXZ 2048          // 2*D_INNER
#define DSTATE 16
#define DTRANK 32
#define NDBL 64           // DT_RANK + 2*D_STATE
#define ML (BB*LL)        // 4096 rows
#define LC 128            // scan chunk length
#define NCHUNK (LL/LC)    // 16 chunks per sequence
#define LCP 132           // padded LDS chunk stride

typedef __bf16 bf16_t;
typedef bf16_t bf16x8 __attribute__((ext_vector_type(8)));
typedef bf16_t bf16x4 __attribute__((ext_vector_type(4)));
typedef float f32x4 __attribute__((ext_vector_type(4)));

#define GBK 32            // MFMA K-step
#define GBKP 40           // padded LDS row stride (bf16): 80B, 16B-aligned, 2-way banks

// ---------------------------------------------------------------------------
// bf16 MFMA GEMM: C[M,N](f32) = A[M,K](bf16) * Bt[N,K](bf16)^T
// 256 threads = 4 waves (2x2). TM x TN block tile, wave tile TM/2 x TN/2.
// CT=1: store C transposed as C[n*ldc+m] (float4 along m).
// MODE 0: plain; MODE 2: + aux[m*ldc+n] residual (CT=0 only).
// ---------------------------------------------------------------------------
template <int TM, int TN, int MODE, int CT>
__launch_bounds__(256)
__global__ void gemm_mfma(const bf16_t* __restrict__ A,
                          const bf16_t* __restrict__ Bt,
                          float* __restrict__ C, int ldc,
                          int M, int N, int K,
                          const float* __restrict__ aux) {
  __shared__ __align__(16) bf16_t As[TM * GBKP];
  __shared__ __align__(16) bf16_t Bs[TN * GBKP];
  const int tid = threadIdx.x;
  const int wid = tid >> 6, lane = tid & 63;
  const int q = lane >> 4, ln = lane & 15;
  constexpr int WM = TM / 2, WN = TN / 2;
  constexpr int FM = WM / 16, FN = WN / 16;
  const int wm = (wid >> 1) * WM, wn = (wid & 1) * WN;
  const int mBase = blockIdx.y * TM, nBase = blockIdx.x * TN;

  f32x4 acc[FM][FN] = {};

  for (int k0 = 0; k0 < K; k0 += GBK) {
#pragma unroll
    for (int i = 0; i < TM * GBK / (256 * 8); i++) {
      const int slot = tid + i * 256;
      const int m = slot >> 2, k8 = (slot & 3) * 8;
      *(bf16x8*)&As[m * GBKP + k8] =
          *(const bf16x8*)&A[(size_t)(mBase + m) * K + k0 + k8];
    }
#pragma unroll
    for (int i = 0; i < TN * GBK / (256 * 8); i++) {
      const int slot = tid + i * 256;
      const int n = slot >> 2, k8 = (slot & 3) * 8;
      *(bf16x8*)&Bs[n * GBKP + k8] =
          *(const bf16x8*)&Bt[(size_t)(nBase + n) * K + k0 + k8];
    }
    __syncthreads();
    bf16x8 af[FM], bfr[FN];
#pragma unroll
    for (int i = 0; i < FM; i++)
      af[i] = *(const bf16x8*)&As[(wm + i * 16 + ln) * GBKP + q * 8];
#pragma unroll
    for (int j = 0; j < FN; j++)
      bfr[j] = *(const bf16x8*)&Bs[(wn + j * 16 + ln) * GBKP + q * 8];
#pragma unroll
    for (int i = 0; i < FM; i++)
#pragma unroll
      for (int j = 0; j < FN; j++)
        acc[i][j] = __builtin_amdgcn_mfma_f32_16x16x32_bf16(
            af[i], bfr[j], acc[i][j], 0, 0, 0);
    __syncthreads();
  }

#pragma unroll
  for (int i = 0; i < FM; i++) {
    const int m0 = mBase + wm + i * 16 + q * 4;   // C/D: row = q*4 + reg
#pragma unroll
    for (int j = 0; j < FN; j++) {
      const int n = nBase + wn + j * 16 + ln;     // C/D: col = lane&15
      if (CT == 1) {
        *(f32x4*)&C[(size_t)n * ldc + m0] = acc[i][j];
      } else {
#pragma unroll
        for (int r = 0; r < 4; r++) {
          float v = acc[i][j][r];
          if (MODE == 2) v += aux[(size_t)(m0 + r) * ldc + n];
          C[(size_t)(m0 + r) * ldc + n] = v;
        }
      }
    }
  }
}

// ---------------------------------------------------------------------------
// Elementwise fp32 -> bf16 cast (float4 -> bf16x4).
// ---------------------------------------------------------------------------
__global__ void cast_bf16(const float* __restrict__ in, bf16_t* __restrict__ out,
                          int n4) {
  const int i = blockIdx.x * 256 + threadIdx.x;
  if (i >= n4) return;
  const float4 v = ((const float4*)in)[i];
  bf16x4 o = {(bf16_t)v.x, (bf16_t)v.y, (bf16_t)v.z, (bf16_t)v.w};
  ((bf16x4*)out)[i] = o;
}

// ---------------------------------------------------------------------------
// Tiled transpose + cast: in fp32 [R][C] -> out bf16 [C][R]. 64x64 tiles.
// ---------------------------------------------------------------------------
__launch_bounds__(256)
__global__ void transpose_cast(const float* __restrict__ in, bf16_t* __restrict__ out,
                               int R, int C) {
  __shared__ float T[64][65];
  const int t = threadIdx.x;
  const int rB = blockIdx.y * 64, cB = blockIdx.x * 64;
  {
    const int r = t >> 4, c4 = (t & 15) * 4;
#pragma unroll
    for (int i = 0; i < 4; i++) {
      const float4 v = *(const float4*)&in[(size_t)(rB + r + i * 16) * C + cB + c4];
      T[r + i * 16][c4] = v.x;
      T[r + i * 16][c4 + 1] = v.y;
      T[r + i * 16][c4 + 2] = v.z;
      T[r + i * 16][c4 + 3] = v.w;
    }
  }
  __syncthreads();
  {
    const int c = t >> 2;
#pragma unroll
    for (int i = 0; i < 4; i++) {
      const int r0 = (t & 3) * 16 + i * 4;
      bf16x4 o = {(bf16_t)T[r0][c], (bf16_t)T[r0 + 1][c],
                  (bf16_t)T[r0 + 2][c], (bf16_t)T[r0 + 3][c]};
      *(bf16x4*)&out[(size_t)(cB + c) * R + rB + r0] = o;
    }
  }
}

// ---------------------------------------------------------------------------
// fp32 tiled GEMM (for the small GEMMs 3 & 4): 64x64 tile, BK=16.
// AT: A layout [m][k] (0) or [k][m] (1). CT: C layout normal (0) / transposed (1).
// MODE 0: plain; 1: softplus(acc+bias[n]); 3: atomicAdd (split-K, gridDim.z).
// ---------------------------------------------------------------------------
template <int MODE, int AT, int CT>
__launch_bounds__(256)
__global__ void gemm_tiled(const float* __restrict__ A, int lda,
                           const float* __restrict__ B, int ldb,
                           float* __restrict__ C, int ldc,
                           int M, int N, int K,
                           const float* __restrict__ aux) {
  __shared__ float As[16][68];
  __shared__ float Bs[16][68];

  const int tid = threadIdx.x;
  const int tx = tid & 15, ty = tid >> 4;
  const int mBase = blockIdx.y * 64;
  const int nBase = blockIdx.x * 64;
  const int kPer = K / gridDim.z;
  const int kBeg = blockIdx.z * kPer;

  float acc[4][4] = {};

  for (int k0 = kBeg; k0 < kBeg + kPer; k0 += 16) {
#pragma unroll
    for (int i = 0; i < 4; i++) {
      int idx = tid + i * 256;
      if (AT == 0) {
        int m = idx >> 4, kk = idx & 15;
        As[kk][m] = A[(size_t)(mBase + m) * lda + k0 + kk];
      } else {
        int kk = idx >> 6, m = idx & 63;
        As[kk][m] = A[(size_t)(k0 + kk) * lda + mBase + m];
      }
    }
#pragma unroll
    for (int i = 0; i < 4; i++) {
      int idx = tid + i * 256;
      int kk = idx >> 6, n = idx & 63;
      Bs[kk][n] = B[(size_t)(k0 + kk) * ldb + nBase + n];
    }
    __syncthreads();
#pragma unroll
    for (int kk = 0; kk < 16; kk++) {
      const float4 a4 = *reinterpret_cast<const float4*>(&As[kk][ty * 4]);
      const float4 b4 = *reinterpret_cast<const float4*>(&Bs[kk][tx * 4]);
      const float a[4] = {a4.x, a4.y, a4.z, a4.w};
      const float b[4] = {b4.x, b4.y, b4.z, b4.w};
#pragma unroll
      for (int i = 0; i < 4; i++)
#pragma unroll
        for (int j = 0; j < 4; j++) acc[i][j] = fmaf(a[i], b[j], acc[i][j]);
    }
    __syncthreads();
  }

  if (CT == 0) {
#pragma unroll
    for (int i = 0; i < 4; i++) {
      const int m = mBase + ty * 4 + i;
      const int n0 = nBase + tx * 4;
      if (MODE == 3) {
#pragma unroll
        for (int j = 0; j < 4; j++)
          atomicAdd(&C[(size_t)m * ldc + n0 + j], acc[i][j]);
      } else {
        float v[4];
#pragma unroll
        for (int j = 0; j < 4; j++) {
          float x = acc[i][j];
          if (MODE == 1) {
            x += aux[n0 + j];
            x = (x > 20.f) ? x : log1pf(expf(x));
          }
          v[j] = x;
        }
        *reinterpret_cast<float4*>(&C[(size_t)m * ldc + n0]) =
            make_float4(v[0], v[1], v[2], v[3]);
      }
    }
  } else {
    const int m0 = mBase + ty * 4;
#pragma unroll
    for (int j = 0; j < 4; j++) {
      const int n = nBase + tx * 4 + j;
      float v[4];
#pragma unroll
      for (int i = 0; i < 4; i++) {
        float x = acc[i][j];
        if (MODE == 1) {
          x += aux[n];
          x = (x > 20.f) ? x : log1pf(expf(x));
        }
        v[i] = x;
      }
      *reinterpret_cast<float4*>(&C[(size_t)n * ldc + m0]) =
          make_float4(v[0], v[1], v[2], v[3]);
    }
  }
}

// ---------------------------------------------------------------------------
// Depthwise causal conv (k=4) + bias + SiLU, transposed layout.
// ---------------------------------------------------------------------------
__launch_bounds__(256)
__global__ void conv_silu_T(const float* __restrict__ xzT,
                            const float* __restrict__ conv_w,
                            const float* __restrict__ conv_b,
                            float* __restrict__ uT) {
  const int idx = blockIdx.x * 256 + threadIdx.x;   // over DIN * ML/4
  const int d = idx >> 10;
  const int ml0 = (idx & 1023) * 4;
  const int l0 = ml0 & (LL - 1);
  const float* row = xzT + (size_t)d * ML + ml0;
  const float4 Bv = *reinterpret_cast<const float4*>(row);
  float4 Av = make_float4(0.f, 0.f, 0.f, 0.f);
  if (l0 != 0) Av = *reinterpret_cast<const float4*>(row - 4);
  const float w0 = conv_w[d * 4 + 0], w1 = conv_w[d * 4 + 1];
  const float w2 = conv_w[d * 4 + 2], w3 = conv_w[d * 4 + 3];
  const float bias = conv_b[d];
  float o[4];
  o[0] = bias + w0 * Av.y + w1 * Av.z + w2 * Av.w + w3 * Bv.x;
  o[1] = bias + w0 * Av.z + w1 * Av.w + w2 * Bv.x + w3 * Bv.y;
  o[2] = bias + w0 * Av.w + w1 * Bv.x + w2 * Bv.y + w3 * Bv.z;
  o[3] = bias + w0 * Bv.x + w1 * Bv.y + w2 * Bv.z + w3 * Bv.w;
#pragma unroll
  for (int i = 0; i < 4; i++) o[i] = o[i] / (1.f + expf(-o[i]));
  *reinterpret_cast<float4*>(uT + (size_t)d * ML + ml0) =
      make_float4(o[0], o[1], o[2], o[3]);
}

// ---------------------------------------------------------------------------
// Fused chunked selective scan (unchanged from R3): one block = one channel.
// ---------------------------------------------------------------------------
__launch_bounds__(256)
__global__ void scan_fused(const float* __restrict__ dtT,
                           const float* __restrict__ uT,
                           float* __restrict__ xzT,
                           const float* __restrict__ xdbl,
                           const float* __restrict__ A_log,
                           const float* __restrict__ D_param) {
  __shared__ float dt_s[NCHUNK * LCP];
  __shared__ float u_s[NCHUNK * LCP];
  __shared__ float zy_s[NCHUNK * LCP];
  __shared__ float Pc[NCHUNK][DSTATE];
  __shared__ float Hc[NCHUNK][DSTATE];
  __shared__ float Hin[NCHUNK][DSTATE];

  const int tid = threadIdx.x;
  const int c = blockIdx.x;
  const int b = c >> 10, d = c & (DIN - 1);
  const size_t rowoff = (size_t)d * ML + (size_t)b * LL;
  const float* dtrow = dtT + rowoff;
  const float* urow = uT + rowoff;
  const float* zrow = xzT + (size_t)(DIN + d) * ML + (size_t)b * LL;
  float* yrow = xzT + rowoff;

  for (int i = tid; i < 512; i += 256) {
    const int ch = i >> 5, off = (i & 31) * 4;
    const int la = ch * LCP + off;
    *reinterpret_cast<float4*>(&dt_s[la]) = *reinterpret_cast<const float4*>(&dtrow[i * 4]);
    *reinterpret_cast<float4*>(&u_s[la])  = *reinterpret_cast<const float4*>(&urow[i * 4]);
    *reinterpret_cast<float4*>(&zy_s[la]) = *reinterpret_cast<const float4*>(&zrow[i * 4]);
  }

  const int g = tid >> 4, s = tid & 15;
  const float Al2 = -expf(A_log[d * DSTATE + s]) * 1.44269504f;
  const float* dp = dt_s + g * LCP;
  const float* up = u_s + g * LCP;
  const float* BCp = xdbl + ((size_t)b * LL + (size_t)g * LC) * NDBL + DTRANK + s;
  __syncthreads();

  {
    float h = 0.f, P = 1.f;
#pragma unroll 4
    for (int l = 0; l < LC; l++) {
      const float dtv = dp[l], uv = up[l];
      const float Bv = BCp[l * NDBL];
      const float dA = exp2f(dtv * Al2);
      P *= dA;
      h = fmaf(h, dA, dtv * uv * Bv);
    }
    Pc[g][s] = P;
    Hc[g][s] = h;
  }
  __syncthreads();

  if (tid < DSTATE) {
    float h = 0.f;
#pragma unroll
    for (int ch = 0; ch < NCHUNK; ch++) {
      Hin[ch][tid] = h;
      h = fmaf(h, Pc[ch][tid], Hc[ch][tid]);
    }
  }
  __syncthreads();

  {
    const float Dp = D_param[d];
    float* zp = zy_s + g * LCP;
    float h = Hin[g][s];
#pragma unroll 2
    for (int l = 0; l < LC; l++) {
      const float dtv = dp[l], uv = up[l];
      const float Bv = BCp[l * NDBL];
      const float Cv = BCp[l * NDBL + DSTATE];
      const float dA = exp2f(dtv * Al2);
      h = fmaf(h, dA, dtv * uv * Bv);
      float p = h * Cv;
      p += __shfl_xor(p, 1);
      p += __shfl_xor(p, 2);
      p += __shfl_xor(p, 4);
      p += __shfl_xor(p, 8);
      if (s == 0) {
        const float zv = zp[l];
        const float sg = 1.f / (1.f + expf(-zv));
        zp[l] = (p + uv * Dp) * (zv * sg);
      }
    }
  }
  __syncthreads();

  for (int i = tid; i < 512; i += 256) {
    const int ch = i >> 5, off = (i & 31) * 4;
    *reinterpret_cast<float4*>(&yrow[i * 4]) =
        *reinterpret_cast<const float4*>(&zy_s[ch * LCP + off]);
  }
}

// ---------------------------------------------------------------------------
extern "C" void kernel_launch(void* const* d_in, const int* in_sizes, int n_in,
                              void* d_out, int out_size, void* d_ws, size_t ws_size,
                              hipStream_t stream) {
  const float* x      = (const float*)d_in[0];
  const float* W_in   = (const float*)d_in[1];
  const float* conv_w = (const float*)d_in[2];
  const float* conv_b = (const float*)d_in[3];
  const float* W_x    = (const float*)d_in[4];
  const float* W_dt   = (const float*)d_in[5];
  const float* b_dt   = (const float*)d_in[6];
  const float* A_log  = (const float*)d_in[7];
  const float* D_par  = (const float*)d_in[8];
  const float* W_out  = (const float*)d_in[9];
  float* out = (float*)d_out;

  char* ws = (char*)d_ws;
  float* xzT   = (float*)(ws);                                  // [2048][4096] 32MB
  float* uT    = (float*)(ws + (size_t)ML * DXZ * 4);           // [1024][4096] 16MB
  float* x_dbl = (float*)(ws + (size_t)ML * (DXZ + DIN) * 4);   // [4096][64]   1MB
  char* dtT_b  = ws + (size_t)ML * (DXZ + DIN + NDBL) * 4;
  float* dtT   = (float*)dtT_b;                                 // [1024][4096] 16MB
  bf16_t* y_b  = (bf16_t*)dtT_b;  // overlays dtT region (dead after scan) 8MB
  char* extra  = ws + (size_t)ML * (DXZ + DIN + NDBL + DIN) * 4;
  bf16_t* x_b      = (bf16_t*)(extra);                          // [4096][512]  4MB
  bf16_t* W_inT_b  = (bf16_t*)(extra + (size_t)ML * DD * 2);    // [2048][512]  2MB
  bf16_t* W_outT_b = (bf16_t*)(extra + (size_t)ML * DD * 2 + (size_t)DXZ * DD * 2); // [512][1024] 1MB

  // 0) casts: x -> bf16; W_in, W_out -> transposed bf16
  cast_bf16<<<(ML * DD / 4) / 256, 256, 0, stream>>>(x, x_b, ML * DD / 4);
  transpose_cast<<<dim3(DXZ / 64, DD / 64), 256, 0, stream>>>(W_in, W_inT_b, DD, DXZ);
  transpose_cast<<<dim3(DD / 64, DIN / 64), 256, 0, stream>>>(W_out, W_outT_b, DIN, DD);

  // 1) xzT = (x @ W_in)^T  via bf16 MFMA, transposed epilogue
  gemm_mfma<128, 128, 0, 1><<<dim3(DXZ / 128, ML / 128), 256, 0, stream>>>(
      x_b, W_inT_b, xzT, ML, ML, DXZ, DD, nullptr);

  // 2) uT = silu(causal_conv4(xzT rows 0..1023) + conv_b)
  conv_silu_T<<<(DIN * (ML / 4)) / 256, 256, 0, stream>>>(xzT, conv_w, conv_b, uT);

  // 3) x_dbl = u @ W_x  (fp32, split-K=4 with atomic accumulate)
  hipMemsetAsync(x_dbl, 0, (size_t)ML * NDBL * 4, stream);
  gemm_tiled<3, 1, 0><<<dim3(NDBL / 64, ML / 64, 4), 256, 0, stream>>>(
      uT, ML, W_x, NDBL, x_dbl, NDBL, ML, NDBL, DIN, nullptr);

  // 4) dtT = softplus(x_dbl[:, :32] @ W_dt + b_dt)^T  (fp32)
  gemm_tiled<1, 0, 1><<<dim3(DIN / 64, ML / 64), 256, 0, stream>>>(
      x_dbl, NDBL, W_dt, DIN, dtT, ML, ML, DIN, DTRANK, b_dt);

  // 5) fused chunked scan + gated epilogue -> xzT rows 0..1023 (= yT, fp32)
  scan_fused<<<BB * DIN, 256, 0, stream>>>(dtT, uT, xzT, x_dbl, A_log, D_par);

  // 5b) y_b = transpose_cast(yT)  -> bf16 [4096][1024] (overlays dead dtT)
  transpose_cast<<<dim3(ML / 64, DIN / 64), 256, 0, stream>>>(xzT, y_b, DIN, ML);

  // 6) out = x + y @ W_out  via bf16 MFMA, residual fused
  gemm_mfma<128, 64, 2, 0><<<dim3(DD / 64, ML / 128), 256, 0, stream>>>(
      y_b, W_outT_b, out, DD, ML, DD, DIN, x);
}

// Round 5
// 251.965 us; speedup vs baseline: 6.5227x; 1.2303x over previous
//
#include <hip/hip_runtime.h>
#include <math.h>

// Problem constants (B=2, L=2048, D=512)
#define BB 2
#define LL 2048
#define DD 512
#define DIN 1024          // D_INNER
#define DXZ 2048          // 2*D_INNER
#define DSTATE 16
#define DTRANK 32
#define NDBL 64           // DT_RANK + 2*D_STATE
#define ML (BB*LL)        // 4096 rows
#define LC2 64            // scan chunk length
#define NCH2 (LL/LC2)     // 32 chunks per sequence
#define CP 68             // padded LDS chunk stride (floats)

typedef __bf16 bf16_t;
typedef bf16_t bf16x8 __attribute__((ext_vector_type(8)));
typedef bf16_t bf16x4 __attribute__((ext_vector_type(4)));
typedef float f32x4 __attribute__((ext_vector_type(4)));

#define GBK 32            // MFMA K-step
#define GBKP 40           // padded LDS row stride (bf16)

__device__ __forceinline__ float fast_silu(float x) {
  return x * __builtin_amdgcn_rcpf(1.f + __builtin_amdgcn_exp2f(-1.44269504f * x));
}

// ---------------------------------------------------------------------------
// bf16 MFMA GEMM: C[M,N](f32) = A[M,K](bf16) * Bt[N,K](bf16)^T
// 256 threads = 4 waves (2x2). CT=1: store C transposed C[n*ldc+m].
// MODE 0: plain; MODE 2: + aux[m*ldc+n] residual (CT=0 only).
// ---------------------------------------------------------------------------
template <int TM, int TN, int MODE, int CT>
__launch_bounds__(256)
__global__ void gemm_mfma(const bf16_t* __restrict__ A,
                          const bf16_t* __restrict__ Bt,
                          float* __restrict__ C, int ldc,
                          int M, int N, int K,
                          const float* __restrict__ aux) {
  __shared__ __align__(16) bf16_t As[TM * GBKP];
  __shared__ __align__(16) bf16_t Bs[TN * GBKP];
  const int tid = threadIdx.x;
  const int wid = tid >> 6, lane = tid & 63;
  const int q = lane >> 4, ln = lane & 15;
  constexpr int WM = TM / 2, WN = TN / 2;
  constexpr int FM = WM / 16, FN = WN / 16;
  const int wm = (wid >> 1) * WM, wn = (wid & 1) * WN;
  const int mBase = blockIdx.y * TM, nBase = blockIdx.x * TN;

  f32x4 acc[FM][FN] = {};

  for (int k0 = 0; k0 < K; k0 += GBK) {
#pragma unroll
    for (int i = 0; i < TM * GBK / (256 * 8); i++) {
      const int slot = tid + i * 256;
      const int m = slot >> 2, k8 = (slot & 3) * 8;
      *(bf16x8*)&As[m * GBKP + k8] =
          *(const bf16x8*)&A[(size_t)(mBase + m) * K + k0 + k8];
    }
#pragma unroll
    for (int i = 0; i < TN * GBK / (256 * 8); i++) {
      const int slot = tid + i * 256;
      const int n = slot >> 2, k8 = (slot & 3) * 8;
      *(bf16x8*)&Bs[n * GBKP + k8] =
          *(const bf16x8*)&Bt[(size_t)(nBase + n) * K + k0 + k8];
    }
    __syncthreads();
    bf16x8 af[FM], bfr[FN];
#pragma unroll
    for (int i = 0; i < FM; i++)
      af[i] = *(const bf16x8*)&As[(wm + i * 16 + ln) * GBKP + q * 8];
#pragma unroll
    for (int j = 0; j < FN; j++)
      bfr[j] = *(const bf16x8*)&Bs[(wn + j * 16 + ln) * GBKP + q * 8];
#pragma unroll
    for (int i = 0; i < FM; i++)
#pragma unroll
      for (int j = 0; j < FN; j++)
        acc[i][j] = __builtin_amdgcn_mfma_f32_16x16x32_bf16(
            af[i], bfr[j], acc[i][j], 0, 0, 0);
    __syncthreads();
  }

#pragma unroll
  for (int i = 0; i < FM; i++) {
    const int m0 = mBase + wm + i * 16 + q * 4;
#pragma unroll
    for (int j = 0; j < FN; j++) {
      const int n = nBase + wn + j * 16 + ln;
      if (CT == 1) {
        *(f32x4*)&C[(size_t)n * ldc + m0] = acc[i][j];
      } else {
#pragma unroll
        for (int r = 0; r < 4; r++) {
          float v = acc[i][j][r];
          if (MODE == 2) v += aux[(size_t)(m0 + r) * ldc + n];
          C[(size_t)(m0 + r) * ldc + n] = v;
        }
      }
    }
  }
}

// ---------------------------------------------------------------------------
// Elementwise fp32 -> bf16 cast.
// ---------------------------------------------------------------------------
__global__ void cast_bf16(const float* __restrict__ in, bf16_t* __restrict__ out,
                          int n4) {
  const int i = blockIdx.x * 256 + threadIdx.x;
  if (i >= n4) return;
  const float4 v = ((const float4*)in)[i];
  bf16x4 o = {(bf16_t)v.x, (bf16_t)v.y, (bf16_t)v.z, (bf16_t)v.w};
  ((bf16x4*)out)[i] = o;
}

// ---------------------------------------------------------------------------
// Tiled transpose + cast: in fp32 [R][C] -> out bf16 [C][R]. 64x64 tiles.
// ---------------------------------------------------------------------------
__launch_bounds__(256)
__global__ void transpose_cast(const float* __restrict__ in, bf16_t* __restrict__ out,
                               int R, int C) {
  __shared__ float T[64][65];
  const int t = threadIdx.x;
  const int rB = blockIdx.y * 64, cB = blockIdx.x * 64;
  {
    const int r = t >> 4, c4 = (t & 15) * 4;
#pragma unroll
    for (int i = 0; i < 4; i++) {
      const float4 v = *(const float4*)&in[(size_t)(rB + r + i * 16) * C + cB + c4];
      T[r + i * 16][c4] = v.x;
      T[r + i * 16][c4 + 1] = v.y;
      T[r + i * 16][c4 + 2] = v.z;
      T[r + i * 16][c4 + 3] = v.w;
    }
  }
  __syncthreads();
  {
    const int c = t >> 2;
#pragma unroll
    for (int i = 0; i < 4; i++) {
      const int r0 = (t & 3) * 16 + i * 4;
      bf16x4 o = {(bf16_t)T[r0][c], (bf16_t)T[r0 + 1][c],
                  (bf16_t)T[r0 + 2][c], (bf16_t)T[r0 + 3][c]};
      *(bf16x4*)&out[(size_t)(cB + c) * R + rB + r0] = o;
    }
  }
}

// ---------------------------------------------------------------------------
// fp32 tiled GEMM (GEMM4 only): 64x64 tile, BK=16.
// MODE 1: softplus(acc+bias[n]); CT=1: transposed store.
// ---------------------------------------------------------------------------
template <int MODE, int AT, int CT>
__launch_bounds__(256)
__global__ void gemm_tiled(const float* __restrict__ A, int lda,
                           const float* __restrict__ B, int ldb,
                           float* __restrict__ C, int ldc,
                           int M, int N, int K,
                           const float* __restrict__ aux) {
  __shared__ float As[16][68];
  __shared__ float Bs[16][68];

  const int tid = threadIdx.x;
  const int tx = tid & 15, ty = tid >> 4;
  const int mBase = blockIdx.y * 64;
  const int nBase = blockIdx.x * 64;

  float acc[4][4] = {};

  for (int k0 = 0; k0 < K; k0 += 16) {
#pragma unroll
    for (int i = 0; i < 4; i++) {
      int idx = tid + i * 256;
      if (AT == 0) {
        int m = idx >> 4, kk = idx & 15;
        As[kk][m] = A[(size_t)(mBase + m) * lda + k0 + kk];
      } else {
        int kk = idx >> 6, m = idx & 63;
        As[kk][m] = A[(size_t)(k0 + kk) * lda + mBase + m];
      }
    }
#pragma unroll
    for (int i = 0; i < 4; i++) {
      int idx = tid + i * 256;
      int kk = idx >> 6, n = idx & 63;
      Bs[kk][n] = B[(size_t)(k0 + kk) * ldb + nBase + n];
    }
    __syncthreads();
#pragma unroll
    for (int kk = 0; kk < 16; kk++) {
      const float4 a4 = *reinterpret_cast<const float4*>(&As[kk][ty * 4]);
      const float4 b4 = *reinterpret_cast<const float4*>(&Bs[kk][tx * 4]);
      const float a[4] = {a4.x, a4.y, a4.z, a4.w};
      const float b[4] = {b4.x, b4.y, b4.z, b4.w};
#pragma unroll
      for (int i = 0; i < 4; i++)
#pragma unroll
        for (int j = 0; j < 4; j++) acc[i][j] = fmaf(a[i], b[j], acc[i][j]);
    }
    __syncthreads();
  }

  if (CT == 0) {
#pragma unroll
    for (int i = 0; i < 4; i++) {
      const int m = mBase + ty * 4 + i;
      const int n0 = nBase + tx * 4;
      float v[4];
#pragma unroll
      for (int j = 0; j < 4; j++) {
        float x = acc[i][j];
        if (MODE == 1) {
          x += aux[n0 + j];
          x = (x > 20.f) ? x
              : 0.69314718f * __builtin_amdgcn_logf(
                    1.f + __builtin_amdgcn_exp2f(x * 1.44269504f));
        }
        v[j] = x;
      }
      *reinterpret_cast<float4*>(&C[(size_t)m * ldc + n0]) =
          make_float4(v[0], v[1], v[2], v[3]);
    }
  } else {
    const int m0 = mBase + ty * 4;
#pragma unroll
    for (int j = 0; j < 4; j++) {
      const int n = nBase + tx * 4 + j;
      float v[4];
#pragma unroll
      for (int i = 0; i < 4; i++) {
        float x = acc[i][j];
        if (MODE == 1) {
          x += aux[n];
          x = (x > 20.f) ? x
              : 0.69314718f * __builtin_amdgcn_logf(
                    1.f + __builtin_amdgcn_exp2f(x * 1.44269504f));
        }
        v[i] = x;
      }
      *reinterpret_cast<float4*>(&C[(size_t)n * ldc + m0]) =
          make_float4(v[0], v[1], v[2], v[3]);
    }
  }
}

// ---------------------------------------------------------------------------
// Depthwise causal conv (k=4) + bias + SiLU, transposed layout.
// ---------------------------------------------------------------------------
__launch_bounds__(256)
__global__ void conv_silu_T(const float* __restrict__ xzT,
                            const float* __restrict__ conv_w,
                            const float* __restrict__ conv_b,
                            float* __restrict__ uT) {
  const int idx = blockIdx.x * 256 + threadIdx.x;   // over DIN * ML/4
  const int d = idx >> 10;
  const int ml0 = (idx & 1023) * 4;
  const int l0 = ml0 & (LL - 1);
  const float* row = xzT + (size_t)d * ML + ml0;
  const float4 Bv = *reinterpret_cast<const float4*>(row);
  float4 Av = make_float4(0.f, 0.f, 0.f, 0.f);
  if (l0 != 0) Av = *reinterpret_cast<const float4*>(row - 4);
  const float w0 = conv_w[d * 4 + 0], w1 = conv_w[d * 4 + 1];
  const float w2 = conv_w[d * 4 + 2], w3 = conv_w[d * 4 + 3];
  const float bias = conv_b[d];
  float o[4];
  o[0] = bias + w0 * Av.y + w1 * Av.z + w2 * Av.w + w3 * Bv.x;
  o[1] = bias + w0 * Av.z + w1 * Av.w + w2 * Bv.x + w3 * Bv.y;
  o[2] = bias + w0 * Av.w + w1 * Bv.x + w2 * Bv.y + w3 * Bv.z;
  o[3] = bias + w0 * Bv.x + w1 * Bv.y + w2 * Bv.z + w3 * Bv.w;
#pragma unroll
  for (int i = 0; i < 4; i++) o[i] = fast_silu(o[i]);
  *reinterpret_cast<float4*>(uT + (size_t)d * ML + ml0) =
      make_float4(o[0], o[1], o[2], o[3]);
}

// ---------------------------------------------------------------------------
// Fused chunked selective scan v2: one block = one (b,d) channel, 128 thr.
// 4 lanes per chunk, 4 states per lane. LC2=64, NCH2=32 chunks.
// Quad-reduce via ds_swizzle (xor 1,2). P via running sum of dt (one exp2
// per chunk per state). z read / y write scalar-scattered (L1/L2-buffered).
// ---------------------------------------------------------------------------
__launch_bounds__(128)
__global__ void scan_fused2(const float* __restrict__ dtT,
                            const float* __restrict__ uT,
                            float* __restrict__ xzT,
                            const float* __restrict__ xdbl,
                            const float* __restrict__ A_log,
                            const float* __restrict__ D_param) {
  __shared__ float dt_s[NCH2 * CP];
  __shared__ float u_s[NCH2 * CP];
  __shared__ float Pc[NCH2][DSTATE];
  __shared__ float Hc[NCH2][DSTATE];
  __shared__ float Hin[NCH2][DSTATE];

  const int tid = threadIdx.x;
  const int c = blockIdx.x;
  const int b = c >> 10, d = c & (DIN - 1);
  const size_t rowoff = (size_t)d * ML + (size_t)b * LL;
  const float* dtrow = dtT + rowoff;
  const float* urow  = uT + rowoff;
  const float* zrow  = xzT + (size_t)(DIN + d) * ML + (size_t)b * LL;
  float* yrow = xzT + rowoff;

  // Stage dt,u rows (2048 floats each), coalesced float4.
#pragma unroll
  for (int i = 0; i < 4; i++) {
    const int idx = (tid + i * 128) * 4;
    const int la = (idx >> 6) * CP + (idx & 63);
    *(float4*)&dt_s[la] = *(const float4*)&dtrow[idx];
    *(float4*)&u_s[la]  = *(const float4*)&urow[idx];
  }

  const int ch = tid >> 2, q = tid & 3;
  const int s0 = q * 4;
  float Al2[4];
#pragma unroll
  for (int k = 0; k < 4; k++)
    Al2[k] = -expf(A_log[d * DSTATE + s0 + k]) * 1.44269504f;
  const float* dp = dt_s + ch * CP;
  const float* up = u_s + ch * CP;
  const float* BC = xdbl + ((size_t)b * LL + (size_t)ch * LC2) * NDBL + DTRANK + s0;
  __syncthreads();

  // Phase 1: local scan (h0=0) -> end-state Hc and decay product Pc.
  {
    float h0 = 0.f, h1 = 0.f, h2 = 0.f, h3 = 0.f, sdt = 0.f;
    float4 B4 = *(const float4*)BC;
#pragma unroll 4
    for (int l = 0; l < LC2; l++) {
      const float4 Bv = B4;
      B4 = *(const float4*)(BC + (size_t)(l + 1) * NDBL);  // prefetch (last read discarded, in-ws)
      const float dtv = dp[l];
      const float dtu = dtv * up[l];
      sdt += dtv;
      const float e0 = __builtin_amdgcn_exp2f(dtv * Al2[0]);
      const float e1 = __builtin_amdgcn_exp2f(dtv * Al2[1]);
      const float e2 = __builtin_amdgcn_exp2f(dtv * Al2[2]);
      const float e3 = __builtin_amdgcn_exp2f(dtv * Al2[3]);
      h0 = fmaf(h0, e0, dtu * Bv.x);
      h1 = fmaf(h1, e1, dtu * Bv.y);
      h2 = fmaf(h2, e2, dtu * Bv.z);
      h3 = fmaf(h3, e3, dtu * Bv.w);
    }
    *(float4*)&Pc[ch][s0] = make_float4(
        __builtin_amdgcn_exp2f(Al2[0] * sdt), __builtin_amdgcn_exp2f(Al2[1] * sdt),
        __builtin_amdgcn_exp2f(Al2[2] * sdt), __builtin_amdgcn_exp2f(Al2[3] * sdt));
    *(float4*)&Hc[ch][s0] = make_float4(h0, h1, h2, h3);
  }
  __syncthreads();

  // Phase 2: serial combine over 32 chunks (16 threads, one per state).
  if (tid < DSTATE) {
    float h = 0.f;
#pragma unroll
    for (int k = 0; k < NCH2; k++) {
      Hin[k][tid] = h;
      h = fmaf(h, Pc[k][tid], Hc[k][tid]);
    }
  }
  __syncthreads();

  // Phase 3: re-scan from Hin, y + gated epilogue, scattered global write.
  {
    const float Dp = D_param[d];
    const float4 H4 = *(const float4*)&Hin[ch][s0];
    float h0 = H4.x, h1 = H4.y, h2 = H4.z, h3 = H4.w;
    float4 B4 = *(const float4*)BC;
    float4 C4 = *(const float4*)(BC + DSTATE);
#pragma unroll 4
    for (int l = 0; l < LC2; l++) {
      const float4 Bv = B4;
      const float4 Cv = C4;
      B4 = *(const float4*)(BC + (size_t)(l + 1) * NDBL);
      C4 = *(const float4*)(BC + (size_t)(l + 1) * NDBL + DSTATE);
      const float dtv = dp[l];
      const float uv = up[l];
      const float dtu = dtv * uv;
      const float e0 = __builtin_amdgcn_exp2f(dtv * Al2[0]);
      const float e1 = __builtin_amdgcn_exp2f(dtv * Al2[1]);
      const float e2 = __builtin_amdgcn_exp2f(dtv * Al2[2]);
      const float e3 = __builtin_amdgcn_exp2f(dtv * Al2[3]);
      h0 = fmaf(h0, e0, dtu * Bv.x);
      h1 = fmaf(h1, e1, dtu * Bv.y);
      h2 = fmaf(h2, e2, dtu * Bv.z);
      h3 = fmaf(h3, e3, dtu * Bv.w);
      float p = fmaf(h0, Cv.x, fmaf(h1, Cv.y, fmaf(h2, Cv.z, h3 * Cv.w)));
      p += __int_as_float(__builtin_amdgcn_ds_swizzle(__float_as_int(p), 0x041F));
      p += __int_as_float(__builtin_amdgcn_ds_swizzle(__float_as_int(p), 0x081F));
      if (q == (l & 3)) {
        const float zv = zrow[ch * LC2 + l];
        yrow[ch * LC2 + l] = (p + uv * Dp) * fast_silu(zv);
      }
    }
  }
}

// ---------------------------------------------------------------------------
extern "C" void kernel_launch(void* const* d_in, const int* in_sizes, int n_in,
                              void* d_out, int out_size, void* d_ws, size_t ws_size,
                              hipStream_t stream) {
  const float* x      = (const float*)d_in[0];
  const float* W_in   = (const float*)d_in[1];
  const float* conv_w = (const float*)d_in[2];
  const float* conv_b = (const float*)d_in[3];
  const float* W_x    = (const float*)d_in[4];
  const float* W_dt   = (const float*)d_in[5];
  const float* b_dt   = (const float*)d_in[6];
  const float* A_log  = (const float*)d_in[7];
  const float* D_par  = (const float*)d_in[8];
  const float* W_out  = (const float*)d_in[9];
  float* out = (float*)d_out;

  char* ws = (char*)d_ws;
  float* xzT   = (float*)(ws);                                  // [2048][4096] 32MB
  float* uT    = (float*)(ws + (size_t)ML * DXZ * 4);           // [1024][4096] 16MB
  float* x_dbl = (float*)(ws + (size_t)ML * (DXZ + DIN) * 4);   // [4096][64]   1MB
  char* dtT_b  = ws + (size_t)ML * (DXZ + DIN + NDBL) * 4;
  float* dtT   = (float*)dtT_b;                                 // [1024][4096] 16MB
  bf16_t* u_b  = (bf16_t*)dtT_b;            // overlay: dead before GEMM4 writes dtT (8MB)
  bf16_t* y_b  = (bf16_t*)(dtT_b + (size_t)ML * DIN * 2);       // overlay: after scan (8MB)
  char* extra  = ws + (size_t)ML * (DXZ + DIN + NDBL + DIN) * 4;
  bf16_t* x_b      = (bf16_t*)(extra);                          // [4096][512]  4MB
  bf16_t* W_inT_b  = (bf16_t*)(extra + (size_t)ML * DD * 2);    // [2048][512]  2MB
  bf16_t* W_outT_b = (bf16_t*)(extra + (size_t)ML * DD * 2 + (size_t)DXZ * DD * 2); // [512][1024] 1MB
  bf16_t* W_xT_b   = (bf16_t*)(extra + (size_t)ML * DD * 2 + (size_t)DXZ * DD * 2
                               + (size_t)DD * DIN * 2);         // [64][1024] 128KB

  // 0) casts / weight transposes
  cast_bf16<<<(ML * DD / 4) / 256, 256, 0, stream>>>(x, x_b, ML * DD / 4);
  transpose_cast<<<dim3(DXZ / 64, DD / 64), 256, 0, stream>>>(W_in, W_inT_b, DD, DXZ);
  transpose_cast<<<dim3(1, DIN / 64), 256, 0, stream>>>(W_x, W_xT_b, DIN, NDBL);
  transpose_cast<<<dim3(DD / 64, DIN / 64), 256, 0, stream>>>(W_out, W_outT_b, DIN, DD);

  // 1) xzT = (x @ W_in)^T  via bf16 MFMA, transposed epilogue
  gemm_mfma<128, 128, 0, 1><<<dim3(DXZ / 128, ML / 128), 256, 0, stream>>>(
      x_b, W_inT_b, xzT, ML, ML, DXZ, DD, nullptr);

  // 2) uT = silu(causal_conv4(xzT rows 0..1023) + conv_b)
  conv_silu_T<<<(DIN * (ML / 4)) / 256, 256, 0, stream>>>(xzT, conv_w, conv_b, uT);

  // 2b) u_b = transpose_cast(uT) -> bf16 [4096][1024]
  transpose_cast<<<dim3(ML / 64, DIN / 64), 256, 0, stream>>>(uT, u_b, DIN, ML);

  // 3) x_dbl = u @ W_x  via bf16 MFMA  (4096x1024)@(1024x64)
  gemm_mfma<64, 64, 0, 0><<<dim3(1, ML / 64), 256, 0, stream>>>(
      u_b, W_xT_b, x_dbl, NDBL, ML, NDBL, DIN, nullptr);

  // 4) dtT = softplus(x_dbl[:, :32] @ W_dt + b_dt)^T  (fp32, K=32)
  gemm_tiled<1, 0, 1><<<dim3(DIN / 64, ML / 64), 256, 0, stream>>>(
      x_dbl, NDBL, W_dt, DIN, dtT, ML, ML, DIN, DTRANK, b_dt);

  // 5) fused chunked scan + gated epilogue -> xzT rows 0..1023 (= yT)
  scan_fused2<<<BB * DIN, 128, 0, stream>>>(dtT, uT, xzT, x_dbl, A_log, D_par);

  // 5b) y_b = transpose_cast(yT) -> bf16 [4096][1024]
  transpose_cast<<<dim3(ML / 64, DIN / 64), 256, 0, stream>>>(xzT, y_b, DIN, ML);

  // 6) out = x + y @ W_out  via bf16 MFMA, residual fused
  gemm_mfma<128, 64, 2, 0><<<dim3(DD / 64, ML / 128), 256, 0, stream>>>(
      y_b, W_outT_b, out, DD, ML, DD, DIN, x);
}

// Round 6
// 225.579 us; speedup vs baseline: 7.2856x; 1.1170x over previous
//
#include <hip/hip_runtime.h>
#include <math.h>

// Problem constants (B=2, L=2048, D=512)
#define BB 2
#define LL 2048
#define DD 512
#define DIN 1024          // D_INNER
#define DXZ 2048          // 2*D_INNER
#define DSTATE 16
#define DTRANK 32
#define NDBL 64           // DT_RANK + 2*D_STATE
#define ML (BB*LL)        // 4096 rows
#define LC2 64            // scan chunk length
#define NCH2 (LL/LC2)     // 32 chunks per sequence
#define CP 68             // padded LDS chunk stride (floats)

typedef __bf16 bf16_t;
typedef bf16_t bf16x8 __attribute__((ext_vector_type(8)));
typedef bf16_t bf16x4 __attribute__((ext_vector_type(4)));
typedef float f32x4 __attribute__((ext_vector_type(4)));

#define GBK 32            // MFMA K-step
#define GBKP 40           // padded LDS row stride (bf16)

__device__ __forceinline__ float fast_silu(float x) {
  return x * __builtin_amdgcn_rcpf(1.f + __builtin_amdgcn_exp2f(-1.44269504f * x));
}

// ---------------------------------------------------------------------------
// bf16 MFMA GEMM: C[M,N](f32) = A[M,K](bf16) * Bt[N,K](bf16)^T
// 256 threads = 4 waves (2x2). CT=1: store C transposed C[n*ldc+m].
// MODE 0: plain; MODE 2: + aux[m*ldc+n] residual (CT=0 only).
// ---------------------------------------------------------------------------
template <int TM, int TN, int MODE, int CT>
__launch_bounds__(256)
__global__ void gemm_mfma(const bf16_t* __restrict__ A,
                          const bf16_t* __restrict__ Bt,
                          float* __restrict__ C, int ldc,
                          int M, int N, int K,
                          const float* __restrict__ aux) {
  __shared__ __align__(16) bf16_t As[TM * GBKP];
  __shared__ __align__(16) bf16_t Bs[TN * GBKP];
  const int tid = threadIdx.x;
  const int wid = tid >> 6, lane = tid & 63;
  const int q = lane >> 4, ln = lane & 15;
  constexpr int WM = TM / 2, WN = TN / 2;
  constexpr int FM = WM / 16, FN = WN / 16;
  const int wm = (wid >> 1) * WM, wn = (wid & 1) * WN;
  const int mBase = blockIdx.y * TM, nBase = blockIdx.x * TN;

  f32x4 acc[FM][FN] = {};

  for (int k0 = 0; k0 < K; k0 += GBK) {
#pragma unroll
    for (int i = 0; i < TM * GBK / (256 * 8); i++) {
      const int slot = tid + i * 256;
      const int m = slot >> 2, k8 = (slot & 3) * 8;
      *(bf16x8*)&As[m * GBKP + k8] =
          *(const bf16x8*)&A[(size_t)(mBase + m) * K + k0 + k8];
    }
#pragma unroll
    for (int i = 0; i < TN * GBK / (256 * 8); i++) {
      const int slot = tid + i * 256;
      const int n = slot >> 2, k8 = (slot & 3) * 8;
      *(bf16x8*)&Bs[n * GBKP + k8] =
          *(const bf16x8*)&Bt[(size_t)(nBase + n) * K + k0 + k8];
    }
    __syncthreads();
    bf16x8 af[FM], bfr[FN];
#pragma unroll
    for (int i = 0; i < FM; i++)
      af[i] = *(const bf16x8*)&As[(wm + i * 16 + ln) * GBKP + q * 8];
#pragma unroll
    for (int j = 0; j < FN; j++)
      bfr[j] = *(const bf16x8*)&Bs[(wn + j * 16 + ln) * GBKP + q * 8];
#pragma unroll
    for (int i = 0; i < FM; i++)
#pragma unroll
      for (int j = 0; j < FN; j++)
        acc[i][j] = __builtin_amdgcn_mfma_f32_16x16x32_bf16(
            af[i], bfr[j], acc[i][j], 0, 0, 0);
    __syncthreads();
  }

#pragma unroll
  for (int i = 0; i < FM; i++) {
    const int m0 = mBase + wm + i * 16 + q * 4;
#pragma unroll
    for (int j = 0; j < FN; j++) {
      const int n = nBase + wn + j * 16 + ln;
      if (CT == 1) {
        *(f32x4*)&C[(size_t)n * ldc + m0] = acc[i][j];
      } else {
#pragma unroll
        for (int r = 0; r < 4; r++) {
          float v = acc[i][j][r];
          if (MODE == 2) v += aux[(size_t)(m0 + r) * ldc + n];
          C[(size_t)(m0 + r) * ldc + n] = v;
        }
      }
    }
  }
}

// ---------------------------------------------------------------------------
// Elementwise fp32 -> bf16 cast.
// ---------------------------------------------------------------------------
__global__ void cast_bf16(const float* __restrict__ in, bf16_t* __restrict__ out,
                          int n4) {
  const int i = blockIdx.x * 256 + threadIdx.x;
  if (i >= n4) return;
  const float4 v = ((const float4*)in)[i];
  bf16x4 o = {(bf16_t)v.x, (bf16_t)v.y, (bf16_t)v.z, (bf16_t)v.w};
  ((bf16x4*)out)[i] = o;
}

// ---------------------------------------------------------------------------
// Tiled transpose + cast: in fp32 [R][C] -> out bf16 [C][R]. 64x64 tiles.
// ---------------------------------------------------------------------------
__launch_bounds__(256)
__global__ void transpose_cast(const float* __restrict__ in, bf16_t* __restrict__ out,
                               int R, int C) {
  __shared__ float T[64][65];
  const int t = threadIdx.x;
  const int rB = blockIdx.y * 64, cB = blockIdx.x * 64;
  {
    const int r = t >> 4, c4 = (t & 15) * 4;
#pragma unroll
    for (int i = 0; i < 4; i++) {
      const float4 v = *(const float4*)&in[(size_t)(rB + r + i * 16) * C + cB + c4];
      T[r + i * 16][c4] = v.x;
      T[r + i * 16][c4 + 1] = v.y;
      T[r + i * 16][c4 + 2] = v.z;
      T[r + i * 16][c4 + 3] = v.w;
    }
  }
  __syncthreads();
  {
    const int c = t >> 2;
#pragma unroll
    for (int i = 0; i < 4; i++) {
      const int r0 = (t & 3) * 16 + i * 4;
      bf16x4 o = {(bf16_t)T[r0][c], (bf16_t)T[r0 + 1][c],
                  (bf16_t)T[r0 + 2][c], (bf16_t)T[r0 + 3][c]};
      *(bf16x4*)&out[(size_t)(cB + c) * R + rB + r0] = o;
    }
  }
}

// ---------------------------------------------------------------------------
// fp32 tiled GEMM (GEMM4 only): 64x64 tile, BK=16.
// MODE 1: softplus(acc+bias[n]); CT=1: transposed store.
// ---------------------------------------------------------------------------
template <int MODE, int AT, int CT>
__launch_bounds__(256)
__global__ void gemm_tiled(const float* __restrict__ A, int lda,
                           const float* __restrict__ B, int ldb,
                           float* __restrict__ C, int ldc,
                           int M, int N, int K,
                           const float* __restrict__ aux) {
  __shared__ float As[16][68];
  __shared__ float Bs[16][68];

  const int tid = threadIdx.x;
  const int tx = tid & 15, ty = tid >> 4;
  const int mBase = blockIdx.y * 64;
  const int nBase = blockIdx.x * 64;

  float acc[4][4] = {};

  for (int k0 = 0; k0 < K; k0 += 16) {
#pragma unroll
    for (int i = 0; i < 4; i++) {
      int idx = tid + i * 256;
      if (AT == 0) {
        int m = idx >> 4, kk = idx & 15;
        As[kk][m] = A[(size_t)(mBase + m) * lda + k0 + kk];
      } else {
        int kk = idx >> 6, m = idx & 63;
        As[kk][m] = A[(size_t)(k0 + kk) * lda + mBase + m];
      }
    }
#pragma unroll
    for (int i = 0; i < 4; i++) {
      int idx = tid + i * 256;
      int kk = idx >> 6, n = idx & 63;
      Bs[kk][n] = B[(size_t)(k0 + kk) * ldb + nBase + n];
    }
    __syncthreads();
#pragma unroll
    for (int kk = 0; kk < 16; kk++) {
      const float4 a4 = *reinterpret_cast<const float4*>(&As[kk][ty * 4]);
      const float4 b4 = *reinterpret_cast<const float4*>(&Bs[kk][tx * 4]);
      const float a[4] = {a4.x, a4.y, a4.z, a4.w};
      const float b[4] = {b4.x, b4.y, b4.z, b4.w};
#pragma unroll
      for (int i = 0; i < 4; i++)
#pragma unroll
        for (int j = 0; j < 4; j++) acc[i][j] = fmaf(a[i], b[j], acc[i][j]);
    }
    __syncthreads();
  }

  if (CT == 0) {
#pragma unroll
    for (int i = 0; i < 4; i++) {
      const int m = mBase + ty * 4 + i;
      const int n0 = nBase + tx * 4;
      float v[4];
#pragma unroll
      for (int j = 0; j < 4; j++) {
        float x = acc[i][j];
        if (MODE == 1) {
          x += aux[n0 + j];
          x = (x > 20.f) ? x
              : 0.69314718f * __builtin_amdgcn_logf(
                    1.f + __builtin_amdgcn_exp2f(x * 1.44269504f));
        }
        v[j] = x;
      }
      *reinterpret_cast<float4*>(&C[(size_t)m * ldc + n0]) =
          make_float4(v[0], v[1], v[2], v[3]);
    }
  } else {
    const int m0 = mBase + ty * 4;
#pragma unroll
    for (int j = 0; j < 4; j++) {
      const int n = nBase + tx * 4 + j;
      float v[4];
#pragma unroll
      for (int i = 0; i < 4; i++) {
        float x = acc[i][j];
        if (MODE == 1) {
          x += aux[n];
          x = (x > 20.f) ? x
              : 0.69314718f * __builtin_amdgcn_logf(
                    1.f + __builtin_amdgcn_exp2f(x * 1.44269504f));
        }
        v[i] = x;
      }
      *reinterpret_cast<float4*>(&C[(size_t)n * ldc + m0]) =
          make_float4(v[0], v[1], v[2], v[3]);
    }
  }
}

// ---------------------------------------------------------------------------
// Depthwise causal conv (k=4) + bias + SiLU, transposed layout.
// ---------------------------------------------------------------------------
__launch_bounds__(256)
__global__ void conv_silu_T(const float* __restrict__ xzT,
                            const float* __restrict__ conv_w,
                            const float* __restrict__ conv_b,
                            float* __restrict__ uT) {
  const int idx = blockIdx.x * 256 + threadIdx.x;   // over DIN * ML/4
  const int d = idx >> 10;
  const int ml0 = (idx & 1023) * 4;
  const int l0 = ml0 & (LL - 1);
  const float* row = xzT + (size_t)d * ML + ml0;
  const float4 Bv = *reinterpret_cast<const float4*>(row);
  float4 Av = make_float4(0.f, 0.f, 0.f, 0.f);
  if (l0 != 0) Av = *reinterpret_cast<const float4*>(row - 4);
  const float w0 = conv_w[d * 4 + 0], w1 = conv_w[d * 4 + 1];
  const float w2 = conv_w[d * 4 + 2], w3 = conv_w[d * 4 + 3];
  const float bias = conv_b[d];
  float o[4];
  o[0] = bias + w0 * Av.y + w1 * Av.z + w2 * Av.w + w3 * Bv.x;
  o[1] = bias + w0 * Av.z + w1 * Av.w + w2 * Bv.x + w3 * Bv.y;
  o[2] = bias + w0 * Av.w + w1 * Bv.x + w2 * Bv.y + w3 * Bv.z;
  o[3] = bias + w0 * Bv.x + w1 * Bv.y + w2 * Bv.z + w3 * Bv.w;
#pragma unroll
  for (int i = 0; i < 4; i++) o[i] = fast_silu(o[i]);
  *reinterpret_cast<float4*>(uT + (size_t)d * ML + ml0) =
      make_float4(o[0], o[1], o[2], o[3]);
}

// ---------------------------------------------------------------------------
// Fused chunked selective scan v3: one block = one (b,d) channel, 128 thr.
// 4 lanes/chunk, 4 states/lane, LC2=64, NCH2=32.
// - 4-deep group-double-buffered B/C prefetch (loads batched per 4 iters).
// - Phase-3 writes pre-gate y' into the dead u_s slot (LDS); the gated
//   z-read / y-write happen in a fully-coalesced float4 epilogue.
// - Hin overwrites Pc in place (LDS 21.5KB -> 7 blocks/CU).
// ---------------------------------------------------------------------------
__launch_bounds__(128, 3)
__global__ void scan_fused3(const float* __restrict__ dtT,
                            const float* __restrict__ uT,
                            float* __restrict__ xzT,
                            const float* __restrict__ xdbl,
                            const float* __restrict__ A_log,
                            const float* __restrict__ D_param) {
  __shared__ float dt_s[NCH2 * CP];
  __shared__ float u_s[NCH2 * CP];      // holds u, then y' after phase 3
  __shared__ float Pc[NCH2][DSTATE];    // decay products, then Hin in place
  __shared__ float Hc[NCH2][DSTATE];

  const int tid = threadIdx.x;
  const int c = blockIdx.x;
  const int b = c >> 10, d = c & (DIN - 1);
  const size_t rowoff = (size_t)d * ML + (size_t)b * LL;
  const float* dtrow = dtT + rowoff;
  const float* urow  = uT + rowoff;
  const float* zrow  = xzT + (size_t)(DIN + d) * ML + (size_t)b * LL;
  float* yrow = xzT + rowoff;

  // Stage dt,u rows (2048 floats each), coalesced float4.
#pragma unroll
  for (int i = 0; i < 4; i++) {
    const int idx = (tid + i * 128) * 4;
    const int la = (idx >> 6) * CP + (idx & 63);
    *(float4*)&dt_s[la] = *(const float4*)&dtrow[idx];
    *(float4*)&u_s[la]  = *(const float4*)&urow[idx];
  }

  const int ch = tid >> 2, q = tid & 3;
  const int s0 = q * 4;
  float Al2[4];
#pragma unroll
  for (int k = 0; k < 4; k++)
    Al2[k] = -expf(A_log[d * DSTATE + s0 + k]) * 1.44269504f;
  const float* dp = dt_s + ch * CP;
  float* up = u_s + ch * CP;
  const float* BC = xdbl + ((size_t)b * LL + (size_t)ch * LC2) * NDBL + DTRANK + s0;
  __syncthreads();

  // Phase 1: local scan (h0=0) -> end-state Hc and decay product Pc.
  {
    float h0 = 0.f, h1 = 0.f, h2 = 0.f, h3 = 0.f, sdt = 0.f;
    float4 Bcur[4];
#pragma unroll
    for (int i = 0; i < 4; i++)
      Bcur[i] = *(const float4*)(BC + (size_t)i * NDBL);
    for (int g = 0; g < 16; g++) {
      float4 Bnxt[4];
      // prefetch next group (g=15 reads a few rows past the chunk: in-ws, unused)
#pragma unroll
      for (int i = 0; i < 4; i++)
        Bnxt[i] = *(const float4*)(BC + (size_t)((g + 1) * 4 + i) * NDBL);
#pragma unroll
      for (int i = 0; i < 4; i++) {
        const int l = g * 4 + i;
        const float dtv = dp[l];
        const float dtu = dtv * up[l];
        sdt += dtv;
        const float e0 = __builtin_amdgcn_exp2f(dtv * Al2[0]);
        const float e1 = __builtin_amdgcn_exp2f(dtv * Al2[1]);
        const float e2 = __builtin_amdgcn_exp2f(dtv * Al2[2]);
        const float e3 = __builtin_amdgcn_exp2f(dtv * Al2[3]);
        h0 = fmaf(h0, e0, dtu * Bcur[i].x);
        h1 = fmaf(h1, e1, dtu * Bcur[i].y);
        h2 = fmaf(h2, e2, dtu * Bcur[i].z);
        h3 = fmaf(h3, e3, dtu * Bcur[i].w);
      }
#pragma unroll
      for (int i = 0; i < 4; i++) Bcur[i] = Bnxt[i];
    }
    *(float4*)&Pc[ch][s0] = make_float4(
        __builtin_amdgcn_exp2f(Al2[0] * sdt), __builtin_amdgcn_exp2f(Al2[1] * sdt),
        __builtin_amdgcn_exp2f(Al2[2] * sdt), __builtin_amdgcn_exp2f(Al2[3] * sdt));
    *(float4*)&Hc[ch][s0] = make_float4(h0, h1, h2, h3);
  }
  __syncthreads();

  // Phase 2: serial combine over 32 chunks; Hin overwrites Pc in place.
  if (tid < DSTATE) {
    float h = 0.f;
#pragma unroll
    for (int k = 0; k < NCH2; k++) {
      const float Pv = Pc[k][tid], Hv = Hc[k][tid];
      Pc[k][tid] = h;                 // Hin for chunk k
      h = fmaf(h, Pv, Hv);
    }
  }
  __syncthreads();

  // Phase 3: re-scan from Hin; write pre-gate y' into u_s (slot l is dead
  // after its same-iteration read — wave lanes are synchronous).
  {
    const float Dp = D_param[d];
    const float4 H4 = *(const float4*)&Pc[ch][s0];
    float h0 = H4.x, h1 = H4.y, h2 = H4.z, h3 = H4.w;
    float4 Bcur[4], Ccur[4];
#pragma unroll
    for (int i = 0; i < 4; i++) {
      Bcur[i] = *(const float4*)(BC + (size_t)i * NDBL);
      Ccur[i] = *(const float4*)(BC + (size_t)i * NDBL + DSTATE);
    }
    for (int g = 0; g < 16; g++) {
      float4 Bnxt[4], Cnxt[4];
#pragma unroll
      for (int i = 0; i < 4; i++) {
        Bnxt[i] = *(const float4*)(BC + (size_t)((g + 1) * 4 + i) * NDBL);
        Cnxt[i] = *(const float4*)(BC + (size_t)((g + 1) * 4 + i) * NDBL + DSTATE);
      }
#pragma unroll
      for (int i = 0; i < 4; i++) {
        const int l = g * 4 + i;
        const float dtv = dp[l];
        const float uv = up[l];
        const float dtu = dtv * uv;
        const float e0 = __builtin_amdgcn_exp2f(dtv * Al2[0]);
        const float e1 = __builtin_amdgcn_exp2f(dtv * Al2[1]);
        const float e2 = __builtin_amdgcn_exp2f(dtv * Al2[2]);
        const float e3 = __builtin_amdgcn_exp2f(dtv * Al2[3]);
        h0 = fmaf(h0, e0, dtu * Bcur[i].x);
        h1 = fmaf(h1, e1, dtu * Bcur[i].y);
        h2 = fmaf(h2, e2, dtu * Bcur[i].z);
        h3 = fmaf(h3, e3, dtu * Bcur[i].w);
        float p = fmaf(h0, Ccur[i].x,
                  fmaf(h1, Ccur[i].y, fmaf(h2, Ccur[i].z, h3 * Ccur[i].w)));
        p += __int_as_float(__builtin_amdgcn_ds_swizzle(__float_as_int(p), 0x041F));
        p += __int_as_float(__builtin_amdgcn_ds_swizzle(__float_as_int(p), 0x081F));
        if (q == (l & 3)) up[l] = p + uv * Dp;   // y' into dead u slot
      }
#pragma unroll
      for (int i = 0; i < 4; i++) { Bcur[i] = Bnxt[i]; Ccur[i] = Cnxt[i]; }
    }
  }
  __syncthreads();

  // Epilogue: coalesced gated write  y = y' * silu(z).
#pragma unroll
  for (int i = 0; i < 4; i++) {
    const int idx = (tid + i * 128) * 4;
    const int la = (idx >> 6) * CP + (idx & 63);
    const float4 y4 = *(const float4*)&u_s[la];
    const float4 z4 = *(const float4*)&zrow[idx];
    float4 o;
    o.x = y4.x * fast_silu(z4.x);
    o.y = y4.y * fast_silu(z4.y);
    o.z = y4.z * fast_silu(z4.z);
    o.w = y4.w * fast_silu(z4.w);
    *(float4*)&yrow[idx] = o;
  }
}

// ---------------------------------------------------------------------------
extern "C" void kernel_launch(void* const* d_in, const int* in_sizes, int n_in,
                              void* d_out, int out_size, void* d_ws, size_t ws_size,
                              hipStream_t stream) {
  const float* x      = (const float*)d_in[0];
  const float* W_in   = (const float*)d_in[1];
  const float* conv_w = (const float*)d_in[2];
  const float* conv_b = (const float*)d_in[3];
  const float* W_x    = (const float*)d_in[4];
  const float* W_dt   = (const float*)d_in[5];
  const float* b_dt   = (const float*)d_in[6];
  const float* A_log  = (const float*)d_in[7];
  const float* D_par  = (const float*)d_in[8];
  const float* W_out  = (const float*)d_in[9];
  float* out = (float*)d_out;

  char* ws = (char*)d_ws;
  float* xzT   = (float*)(ws);                                  // [2048][4096] 32MB
  float* uT    = (float*)(ws + (size_t)ML * DXZ * 4);           // [1024][4096] 16MB
  float* x_dbl = (float*)(ws + (size_t)ML * (DXZ + DIN) * 4);   // [4096][64]   1MB
  char* dtT_b  = ws + (size_t)ML * (DXZ + DIN + NDBL) * 4;
  float* dtT   = (float*)dtT_b;                                 // [1024][4096] 16MB
  bf16_t* u_b  = (bf16_t*)dtT_b;            // overlay: dead before GEMM4 writes dtT (8MB)
  bf16_t* y_b  = (bf16_t*)(dtT_b + (size_t)ML * DIN * 2);       // overlay: after scan (8MB)
  char* extra  = ws + (size_t)ML * (DXZ + DIN + NDBL + DIN) * 4;
  bf16_t* x_b      = (bf16_t*)(extra);                          // [4096][512]  4MB
  bf16_t* W_inT_b  = (bf16_t*)(extra + (size_t)ML * DD * 2);    // [2048][512]  2MB
  bf16_t* W_outT_b = (bf16_t*)(extra + (size_t)ML * DD * 2 + (size_t)DXZ * DD * 2); // [512][1024] 1MB
  bf16_t* W_xT_b   = (bf16_t*)(extra + (size_t)ML * DD * 2 + (size_t)DXZ * DD * 2
                               + (size_t)DD * DIN * 2);         // [64][1024] 128KB

  // 0) casts / weight transposes
  cast_bf16<<<(ML * DD / 4) / 256, 256, 0, stream>>>(x, x_b, ML * DD / 4);
  transpose_cast<<<dim3(DXZ / 64, DD / 64), 256, 0, stream>>>(W_in, W_inT_b, DD, DXZ);
  transpose_cast<<<dim3(1, DIN / 64), 256, 0, stream>>>(W_x, W_xT_b, DIN, NDBL);
  transpose_cast<<<dim3(DD / 64, DIN / 64), 256, 0, stream>>>(W_out, W_outT_b, DIN, DD);

  // 1) xzT = (x @ W_in)^T  via bf16 MFMA, transposed epilogue
  gemm_mfma<128, 128, 0, 1><<<dim3(DXZ / 128, ML / 128), 256, 0, stream>>>(
      x_b, W_inT_b, xzT, ML, ML, DXZ, DD, nullptr);

  // 2) uT = silu(causal_conv4(xzT rows 0..1023) + conv_b)
  conv_silu_T<<<(DIN * (ML / 4)) / 256, 256, 0, stream>>>(xzT, conv_w, conv_b, uT);

  // 2b) u_b = transpose_cast(uT) -> bf16 [4096][1024]
  transpose_cast<<<dim3(ML / 64, DIN / 64), 256, 0, stream>>>(uT, u_b, DIN, ML);

  // 3) x_dbl = u @ W_x  via bf16 MFMA  (4096x1024)@(1024x64)
  gemm_mfma<64, 64, 0, 0><<<dim3(1, ML / 64), 256, 0, stream>>>(
      u_b, W_xT_b, x_dbl, NDBL, ML, NDBL, DIN, nullptr);

  // 4) dtT = softplus(x_dbl[:, :32] @ W_dt + b_dt)^T  (fp32, K=32)
  gemm_tiled<1, 0, 1><<<dim3(DIN / 64, ML / 64), 256, 0, stream>>>(
      x_dbl, NDBL, W_dt, DIN, dtT, ML, ML, DIN, DTRANK, b_dt);

  // 5) fused chunked scan + gated epilogue -> xzT rows 0..1023 (= yT)
  scan_fused3<<<BB * DIN, 128, 0, stream>>>(dtT, uT, xzT, x_dbl, A_log, D_par);

  // 5b) y_b = transpose_cast(yT) -> bf16 [4096][1024]
  transpose_cast<<<dim3(ML / 64, DIN / 64), 256, 0, stream>>>(xzT, y_b, DIN, ML);

  // 6) out = x + y @ W_out  via bf16 MFMA, residual fused
  gemm_mfma<128, 64, 2, 0><<<dim3(DD / 64, ML / 128), 256, 0, stream>>>(
      y_b, W_outT_b, out, DD, ML, DD, DIN, x);
}